// Round 17
// baseline (307.920 us; speedup 1.0000x reference)
//
#include <hip/hip_runtime.h>
#include <cstddef>
#include <cstdint>

// Problem constants
static constexpr int M_ROWS  = 32768;   // B*T
static constexpr int D_INK   = 1024;
static constexpr int D_HID   = 512;
static constexpr int D_CODE_ = 256;
static constexpr int N_CODES_= 128;

// fp16 single-product pairwise-d2 gap jitter sigma ~= 0.023 -> TAU = 6.5 sigma
static constexpr float TAU_GAP = 0.15f;
// fp16 3-product jitter sigma ~= 5e-4 -> TAU2 = 10 sigma
static constexpr float TAU2_GAP = 0.005f;

using f16x8 = __attribute__((ext_vector_type(8))) _Float16;
using f32x4 = __attribute__((ext_vector_type(4))) float;
using f32x2 = __attribute__((ext_vector_type(2))) float;

__device__ __forceinline__ float rdlane(float v, int kk) {
    return __uint_as_float(__builtin_amdgcn_readlane(__float_as_uint(v), kk));
}

// ---------------------------------------------------------------------------
// Packed panel format: one panel = one (128-row tile) x (32-k step):
//   panel[(kq*128 + rc)*8 + j] = src[tile*128 + rc][ks*32 + kq*8 + j]
// ---------------------------------------------------------------------------

__device__ __forceinline__ void dma16(const void* g, void* l) {
    __builtin_amdgcn_global_load_lds(
        (const __attribute__((address_space(1))) void*)g,
        (__attribute__((address_space(3))) void*)l, 16, 0, 0);
}

// stage one 8 KB panel into LDS: 8 dma16 instrs, 2 per wave, lane-contiguous
__device__ __forceinline__ void stage_panel(const _Float16* __restrict__ p,
                                            _Float16* dst, int w, int lane)
{
    #pragma unroll
    for (int ii = 0; ii < 2; ++ii) {
        const int I = 2 * w + ii;           // 0..7 (wave-uniform)
        dma16(p + (size_t)I * 512 + lane * 8, dst + (size_t)I * 512);
    }
}

// one BK=32 compute step: 4x4 fragment tile per wave, single fp16 product
__device__ __forceinline__ void mfma_tile(const _Float16* sA, const _Float16* sB,
                                          int wm, int wn, int kq, int lm,
                                          f32x4 (&acc)[4][4])
{
    f16x8 a[4];
    #pragma unroll
    for (int fm = 0; fm < 4; ++fm)
        a[fm] = *(const f16x8*)(sA + (kq * 128 + wm * 64 + fm * 16 + lm) * 8);
    #pragma unroll
    for (int fn = 0; fn < 4; ++fn) {
        const f16x8 b = *(const f16x8*)(sB + (kq * 128 + wn * 64 + fn * 16 + lm) * 8);
        #pragma unroll
        for (int fm = 0; fm < 4; ++fm)
            acc[fm][fn] = __builtin_amdgcn_mfma_f32_16x16x32_f16(a[fm], b, acc[fm][fn], 0, 0, 0);
    }
}

// 3-product hi/lo step (~fp32 accuracy): ah*bh + al*bh + ah*bl
__device__ __forceinline__ void mfma_tile3(const _Float16* sAh, const _Float16* sAl,
                                           const _Float16* sBh, const _Float16* sBl,
                                           int wm, int wn, int kq, int lm,
                                           f32x4 (&acc)[4][4])
{
    f16x8 ah[4], al[4];
    #pragma unroll
    for (int fm = 0; fm < 4; ++fm) {
        const int fA = kq * 128 + wm * 64 + fm * 16 + lm;
        ah[fm] = *(const f16x8*)(sAh + fA * 8);
        al[fm] = *(const f16x8*)(sAl + fA * 8);
    }
    #pragma unroll
    for (int fn = 0; fn < 4; ++fn) {
        const int fB = kq * 128 + wn * 64 + fn * 16 + lm;
        const f16x8 bh = *(const f16x8*)(sBh + fB * 8);
        const f16x8 bl = *(const f16x8*)(sBl + fB * 8);
        #pragma unroll
        for (int fm = 0; fm < 4; ++fm) {
            acc[fm][fn] = __builtin_amdgcn_mfma_f32_16x16x32_f16(ah[fm], bh, acc[fm][fn], 0, 0, 0);
            acc[fm][fn] = __builtin_amdgcn_mfma_f32_16x16x32_f16(al[fm], bh, acc[fm][fn], 0, 0, 0);
            acc[fm][fn] = __builtin_amdgcn_mfma_f32_16x16x32_f16(ah[fm], bl, acc[fm][fn], 0, 0, 0);
        }
    }
}

// bijective XCD swizzle (nwg % 8 == 0)
__device__ __forceinline__ int xcd_swz(int bid, int nwg) {
    const int q = nwg >> 3;
    return (bid & 7) * q + (bid >> 3);
}

// ---------------------------------------------------------------------------
// prep: codebook -> packed fp16 hi/lo panels + fp32 transposed copy,
// exact per-code norms, zero accums/counters.
// ---------------------------------------------------------------------------
__global__ __launch_bounds__(256)
void prep_cb_kernel(const float* __restrict__ cb, _Float16* __restrict__ cbP,
                    _Float16* __restrict__ cbPl, float* __restrict__ cbT,
                    float* __restrict__ cbnorm, float* __restrict__ accum,
                    int* __restrict__ cnt, int* __restrict__ cnt2)
{
    const int j = blockIdx.x;      // code 0..127
    const int t = threadIdx.x;     // dim 0..255
    const float v = cb[j * D_CODE_ + t];
    const int ks = t >> 5, kq = (t >> 3) & 3, jj = t & 7;
    const _Float16 hi = (_Float16)v;
    cbP [((size_t)ks * 512 + kq * 128 + j) * 8 + jj] = hi;
    cbPl[((size_t)ks * 512 + kq * 128 + j) * 8 + jj] = (_Float16)(v - (float)hi);
    cbT[(size_t)t * N_CODES_ + j] = v;

    __shared__ float sr[256];
    sr[t] = v * v;
    __syncthreads();
    for (int s = 128; s >= 1; s >>= 1) {
        if (t < s) sr[t] += sr[t + s];
        __syncthreads();
    }
    if (t == 0) cbnorm[j] = sr[0];
    if (j == 0 && t < 2) accum[t] = 0.0f;
    if (j == 0 && t == 2) *cnt = 0;
    if (j == 0 && t == 3) *cnt2 = 0;
}

// ---------------------------------------------------------------------------
// pack_w: W [K][N] fp32 -> hi AND lo fp16 B-side panels.
// ---------------------------------------------------------------------------
__global__ __launch_bounds__(256)
void pack_w_kernel(const float* __restrict__ W, _Float16* __restrict__ WPh,
                   _Float16* __restrict__ WPl, int Kd, int Nd)
{
    const int ks = blockIdx.x, nt = blockIdx.y;
    const int t = threadIdx.x;
    const size_t pbase = ((size_t)nt * (Kd >> 5) + ks) * 4096;
    #pragma unroll
    for (int half = 0; half < 2; ++half) {
        const int f = half * 256 + t;
        const int nc = f & 127, kq = f >> 7;
        f16x8 vh, vl;
        #pragma unroll
        for (int j = 0; j < 8; ++j) {
            const float w = W[(size_t)(ks * 32 + kq * 8 + j) * Nd + nt * 128 + nc];
            const _Float16 hi = (_Float16)w;
            vh[j] = hi;
            vl[j] = (_Float16)(w - (float)hi);
        }
        *(f16x8*)(WPh + pbase + (size_t)f * 8) = vh;
        *(f16x8*)(WPl + pbase + (size_t)f * 8) = vl;
    }
}

// ---------------------------------------------------------------------------
// pack_x: x fp32 [M][1024] -> A-side fp16 panels (main path, hi only).
// ---------------------------------------------------------------------------
__global__ __launch_bounds__(256)
void pack_x_kernel(const float* __restrict__ X, _Float16* __restrict__ XP)
{
    __shared__ _Float16 sh[128][136];
    const int t  = threadIdx.x;
    const int mt = blockIdx.x;
    const int kc = blockIdx.y;

    const float* src = X + (size_t)mt * 128 * D_INK + kc * 128;
    #pragma unroll
    for (int i = 0; i < 16; ++i) {
        const int idx = i * 256 + t;
        const int row = idx >> 5, c4 = idx & 31;
        const float4 v = *(const float4*)(src + (size_t)row * D_INK + c4 * 4);
        _Float16* d = &sh[row][c4 * 4];
        d[0] = (_Float16)v.x; d[1] = (_Float16)v.y;
        d[2] = (_Float16)v.z; d[3] = (_Float16)v.w;
    }
    __syncthreads();

    _Float16* dst = XP + ((size_t)mt * 32 + kc * 4) * 4096;
    #pragma unroll
    for (int s = 0; s < 4; ++s) {
        #pragma unroll
        for (int half = 0; half < 2; ++half) {
            const int f = half * 256 + t;
            const int rc = f & 127, kq = f >> 7;
            const f16x8 v = *(const f16x8*)(&sh[rc][s * 32 + kq * 8]);
            *(f16x8*)(dst + (size_t)s * 4096 + (size_t)f * 8) = v;
        }
    }
}

// ---------------------------------------------------------------------------
// GEMM1 (main): h = relu(x @ W1 + b1).
// ---------------------------------------------------------------------------
__global__ __launch_bounds__(256, 4)
void gemm1_kernel(const _Float16* __restrict__ AP, const _Float16* __restrict__ BP,
                  const float* __restrict__ bias, _Float16* __restrict__ CP)
{
    __shared__ _Float16 lds[2][2][4096];

    const int tid  = threadIdx.x;
    const int lane = tid & 63;
    const int w    = tid >> 6;
    const int wm = w >> 1, wn = w & 1;
    const int kq = lane >> 4, lm = lane & 15;

    const int swz = xcd_swz(blockIdx.x, (M_ROWS / 128) * (D_HID / 128));
    const int n0 = (swz & 3) * 128;
    const int m0 = (swz >> 2) * 128;

    const _Float16* Apan = AP + ((size_t)(m0 >> 7) * 32) * 4096;
    const _Float16* Bpan = BP + ((size_t)(n0 >> 7) * 32) * 4096;

    f32x4 acc[4][4] = {};

    stage_panel(Apan, &lds[0][0][0], w, lane);
    stage_panel(Bpan, &lds[0][1][0], w, lane);

    constexpr int NSTEP = D_INK / 32;
    for (int t = 0; t < NSTEP; ++t) {
        const int cur = t & 1, nxt = cur ^ 1;
        __syncthreads();
        if (t + 1 < NSTEP) {
            stage_panel(Apan + (size_t)(t + 1) * 4096, &lds[nxt][0][0], w, lane);
            stage_panel(Bpan + (size_t)(t + 1) * 4096, &lds[nxt][1][0], w, lane);
        }
        mfma_tile(&lds[cur][0][0], &lds[cur][1][0], wm, wn, kq, lm, acc);
    }

    #pragma unroll
    for (int fn = 0; fn < 4; ++fn) {
        const int col = n0 + wn * 64 + fn * 16 + lm;
        const float bv = bias[col];
        #pragma unroll
        for (int fm = 0; fm < 4; ++fm) {
            #pragma unroll
            for (int r = 0; r < 4; ++r) {
                const int row = m0 + wm * 64 + fm * 16 + kq * 4 + r;
                const float v = fmaxf(acc[fm][fn][r] + bv, 0.0f);
                CP[(((size_t)(row >> 7) * 16 + (col >> 5)) * 512
                    + (size_t)((col >> 3) & 3) * 128 + (row & 127)) * 8 + (col & 7)]
                    = (_Float16)v;
            }
        }
    }
}

// ---------------------------------------------------------------------------
// GEMM2 (main): enc = h @ W2 + b2 (+ sum(enc^2) atomic).
// ---------------------------------------------------------------------------
__global__ __launch_bounds__(256, 4)
void gemm2_kernel(const _Float16* __restrict__ AP, const _Float16* __restrict__ BP,
                  const float* __restrict__ bias, _Float16* __restrict__ CP,
                  float* __restrict__ accum)
{
    __shared__ _Float16 lds[2][2][4096];

    const int tid  = threadIdx.x;
    const int lane = tid & 63;
    const int w    = tid >> 6;
    const int wm = w >> 1, wn = w & 1;
    const int kq = lane >> 4, lm = lane & 15;

    const int swz = xcd_swz(blockIdx.x, (M_ROWS / 128) * (D_CODE_ / 128));
    const int n0 = (swz & 1) * 128;
    const int m0 = (swz >> 1) * 128;

    const _Float16* Apan = AP + ((size_t)(m0 >> 7) * 16) * 4096;
    const _Float16* Bpan = BP + ((size_t)(n0 >> 7) * 16) * 4096;

    f32x4 acc[4][4] = {};

    stage_panel(Apan, &lds[0][0][0], w, lane);
    stage_panel(Bpan, &lds[0][1][0], w, lane);

    constexpr int NSTEP = D_HID / 32;
    for (int t = 0; t < NSTEP; ++t) {
        const int cur = t & 1, nxt = cur ^ 1;
        __syncthreads();
        if (t + 1 < NSTEP) {
            stage_panel(Apan + (size_t)(t + 1) * 4096, &lds[nxt][0][0], w, lane);
            stage_panel(Bpan + (size_t)(t + 1) * 4096, &lds[nxt][1][0], w, lane);
        }
        mfma_tile(&lds[cur][0][0], &lds[cur][1][0], wm, wn, kq, lm, acc);
    }

    float sumsq = 0.0f;
    #pragma unroll
    for (int fn = 0; fn < 4; ++fn) {
        const int col = n0 + wn * 64 + fn * 16 + lm;
        const float bv = bias[col];
        #pragma unroll
        for (int fm = 0; fm < 4; ++fm) {
            #pragma unroll
            for (int r = 0; r < 4; ++r) {
                const int row = m0 + wm * 64 + fm * 16 + kq * 4 + r;
                const float v = acc[fm][fn][r] + bv;
                sumsq = fmaf(v, v, sumsq);
                CP[(((size_t)(row >> 7) * 8 + (col >> 5)) * 512
                    + (size_t)((col >> 3) & 3) * 128 + (row & 127)) * 8 + (col & 7)]
                    = (_Float16)v;
            }
        }
    }
    #pragma unroll
    for (int mk = 1; mk <= 32; mk <<= 1) sumsq += __shfl_xor(sumsq, mk);
    if (lane == 0) atomicAdd(&accum[1], sumsq);
}

// ---------------------------------------------------------------------------
// dist (main): argmin + gap flagging + min-term loss sum.
// ---------------------------------------------------------------------------
__global__ __launch_bounds__(256, 4)
void dist_kernel(const _Float16* __restrict__ AP, const _Float16* __restrict__ BP,
                 const float* __restrict__ cbn,
                 float* __restrict__ outIdx, float* __restrict__ accum,
                 int* __restrict__ cnt, int* __restrict__ list)
{
    __shared__ _Float16 lds[2][2][4096];

    const int tid  = threadIdx.x;
    const int lane = tid & 63;
    const int w    = tid >> 6;
    const int wm = w >> 1, wn = w & 1;
    const int kq = lane >> 4, lm = lane & 15;
    const int m0 = blockIdx.x * 128;

    float cbn_l[4];
    #pragma unroll
    for (int fn = 0; fn < 4; ++fn) cbn_l[fn] = cbn[wn * 64 + fn * 16 + lm];

    const _Float16* Apan = AP + ((size_t)(m0 >> 7) * 8) * 4096;

    f32x4 acc[4][4] = {};

    stage_panel(Apan, &lds[0][0][0], w, lane);
    stage_panel(BP,   &lds[0][1][0], w, lane);

    constexpr int NSTEP = D_CODE_ / 32;
    for (int t = 0; t < NSTEP; ++t) {
        const int cur = t & 1, nxt = cur ^ 1;
        __syncthreads();
        if (t + 1 < NSTEP) {
            stage_panel(Apan + (size_t)(t + 1) * 4096, &lds[nxt][0][0], w, lane);
            stage_panel(BP   + (size_t)(t + 1) * 4096, &lds[nxt][1][0], w, lane);
        }
        mfma_tile(&lds[cur][0][0], &lds[cur][1][0], wm, wn, kq, lm, acc);
    }

    __syncthreads();
    float* eb1 = (float*)&lds[0][0][0];        // [2][128]
    float* eb2 = eb1 + 256;
    int*   eix = (int*)(eb2 + 256);

    #pragma unroll
    for (int fm = 0; fm < 4; ++fm) {
        #pragma unroll
        for (int r = 0; r < 4; ++r) {
            float b1v = 3.4e38f, b2v = 3.4e38f; int bi = 0;
            #pragma unroll
            for (int fn = 0; fn < 4; ++fn) {
                const float v = fmaf(-2.0f, acc[fm][fn][r], cbn_l[fn]);
                if (v < b1v) { b2v = b1v; b1v = v; bi = wn * 64 + fn * 16 + lm; }
                else if (v < b2v) b2v = v;
            }
            #pragma unroll
            for (int mk = 1; mk <= 8; mk <<= 1) {
                const float o1 = __shfl_xor(b1v, mk);
                const float o2 = __shfl_xor(b2v, mk);
                const int   oi = __shfl_xor(bi,  mk);
                if (o1 < b1v || (o1 == b1v && oi < bi)) { b2v = fminf(b1v, o2); b1v = o1; bi = oi; }
                else b2v = fminf(b2v, o1);
            }
            const int rl = wm * 64 + fm * 16 + kq * 4 + r;
            if (lm == 0) { eb1[wn * 128 + rl] = b1v; eb2[wn * 128 + rl] = b2v; eix[wn * 128 + rl] = bi; }
        }
    }
    __syncthreads();

    if (tid < 128) {
        const int rl = tid;
        const float a1 = eb1[rl], a2 = eb2[rl]; const int ai = eix[rl];
        const float o1 = eb1[128 + rl], o2 = eb2[128 + rl]; const int oi = eix[128 + rl];
        float B1, B2; int BI;
        if (o1 < a1 || (o1 == a1 && oi < ai)) { B1 = o1; BI = oi; B2 = fminf(a1, o2); }
        else                                  { B1 = a1; BI = ai; B2 = fminf(a2, o1); }
        outIdx[m0 + rl] = (float)BI;
        if (B2 - B1 < TAU_GAP) {
            const int p = atomicAdd(cnt, 1);
            if (p < 32768) list[p] = m0 + rl;
        }
        float s = B1;
        #pragma unroll
        for (int mk = 1; mk <= 32; mk <<= 1) s += __shfl_xor(s, mk);
        if (lane == 0) atomicAdd(&accum[0], s);
    }
}

// ---------------------------------------------------------------------------
// gather_pack_fix: flagged x rows -> hi/lo fp16 A-side panels (padded with
// row list[n-1]).  grid (128, 8): half-tile of 64 rows x 128-k chunk.
// ---------------------------------------------------------------------------
__global__ __launch_bounds__(256)
void gather_pack_fix_kernel(const float* __restrict__ X,
                            const int* __restrict__ list, const int* __restrict__ cnt,
                            _Float16* __restrict__ XH, _Float16* __restrict__ XL)
{
    __shared__ _Float16 shh[64][136];
    __shared__ _Float16 shl[64][136];
    const int n = *cnt;
    if (n == 0) return;
    const int ntp = (n + 127) >> 7;          // full 128-row tiles (padded)
    const int ht = blockIdx.x;                // half tile 0..127
    if (ht >= ntp * 2) return;
    const int kc = blockIdx.y;                // 0..7
    const int t = threadIdx.x;

    #pragma unroll
    for (int i = 0; i < 8; ++i) {
        const int idx = i * 256 + t;          // 0..2047 float4 slots
        const int rl = idx >> 5;              // 0..63
        const int c4 = idx & 31;
        const int slot = ht * 64 + rl;
        const int srcrow = list[slot < n ? slot : n - 1];
        const float4 v = *(const float4*)(X + (size_t)srcrow * D_INK + kc * 128 + c4 * 4);
        _Float16* dh = &shh[rl][c4 * 4];
        _Float16* dl = &shl[rl][c4 * 4];
        const float vv[4] = {v.x, v.y, v.z, v.w};
        #pragma unroll
        for (int q = 0; q < 4; ++q) {
            const _Float16 hi = (_Float16)vv[q];
            dh[q] = hi;
            dl[q] = (_Float16)(vv[q] - (float)hi);
        }
    }
    __syncthreads();

    const int rl = t & 63, kq = t >> 6;       // 64 rows x 4 kq
    const int rc = (ht & 1) * 64 + rl;
    const size_t pb = ((size_t)(ht >> 1) * 32 + kc * 4) * 4096;
    #pragma unroll
    for (int s = 0; s < 4; ++s) {
        const size_t off = pb + (size_t)s * 4096 + (size_t)(kq * 128 + rc) * 8;
        *(f16x8*)(XH + off) = *(const f16x8*)(&shh[rl][s * 32 + kq * 8]);
        *(f16x8*)(XL + off) = *(const f16x8*)(&shl[rl][s * 32 + kq * 8]);
    }
}

// ---------------------------------------------------------------------------
// gemm1_fix: h_fix(hi/lo) = relu(x_fix @ W1 + b1), fp16 3-product MFMA.
// grid (64, 4); blocks past the flagged-tile count exit.
// ---------------------------------------------------------------------------
__global__ __launch_bounds__(256, 2)
void gemm1_fix_kernel(const _Float16* __restrict__ AH, const _Float16* __restrict__ AL,
                      const _Float16* __restrict__ BH, const _Float16* __restrict__ BL,
                      const float* __restrict__ bias,
                      _Float16* __restrict__ CH, _Float16* __restrict__ CL,
                      const int* __restrict__ cnt)
{
    __shared__ _Float16 lds[2][4][4096];   // 64 KB
    const int n = *cnt;
    const int ntp = (n + 127) >> 7;
    if ((int)blockIdx.x >= ntp) return;

    const int tid  = threadIdx.x;
    const int lane = tid & 63;
    const int w    = tid >> 6;
    const int wm = w >> 1, wn = w & 1;
    const int kq = lane >> 4, lm = lane & 15;
    const int m0 = blockIdx.x * 128;
    const int n0 = blockIdx.y * 128;

    const _Float16* Ah = AH + ((size_t)blockIdx.x * 32) * 4096;
    const _Float16* Al = AL + ((size_t)blockIdx.x * 32) * 4096;
    const _Float16* Bh = BH + ((size_t)blockIdx.y * 32) * 4096;
    const _Float16* Bl = BL + ((size_t)blockIdx.y * 32) * 4096;

    f32x4 acc[4][4] = {};

    stage_panel(Ah, &lds[0][0][0], w, lane);
    stage_panel(Al, &lds[0][1][0], w, lane);
    stage_panel(Bh, &lds[0][2][0], w, lane);
    stage_panel(Bl, &lds[0][3][0], w, lane);

    constexpr int NSTEP = D_INK / 32;
    for (int t = 0; t < NSTEP; ++t) {
        const int cur = t & 1, nxt = cur ^ 1;
        __syncthreads();
        if (t + 1 < NSTEP) {
            stage_panel(Ah + (size_t)(t + 1) * 4096, &lds[nxt][0][0], w, lane);
            stage_panel(Al + (size_t)(t + 1) * 4096, &lds[nxt][1][0], w, lane);
            stage_panel(Bh + (size_t)(t + 1) * 4096, &lds[nxt][2][0], w, lane);
            stage_panel(Bl + (size_t)(t + 1) * 4096, &lds[nxt][3][0], w, lane);
        }
        mfma_tile3(&lds[cur][0][0], &lds[cur][1][0], &lds[cur][2][0], &lds[cur][3][0],
                   wm, wn, kq, lm, acc);
    }

    #pragma unroll
    for (int fn = 0; fn < 4; ++fn) {
        const int col = n0 + wn * 64 + fn * 16 + lm;
        const float bv = bias[col];
        #pragma unroll
        for (int fm = 0; fm < 4; ++fm) {
            #pragma unroll
            for (int r = 0; r < 4; ++r) {
                const int row = m0 + wm * 64 + fm * 16 + kq * 4 + r;
                const float v = fmaxf(acc[fm][fn][r] + bv, 0.0f);
                const _Float16 hi = (_Float16)v;
                const size_t idx = (((size_t)(row >> 7) * 16 + (col >> 5)) * 512
                    + (size_t)((col >> 3) & 3) * 128 + (row & 127)) * 8 + (col & 7);
                CH[idx] = hi;
                CL[idx] = (_Float16)(v - (float)hi);
            }
        }
    }
}

// ---------------------------------------------------------------------------
// gemm2_fix: enc_fix(hi/lo) = h_fix @ W2 + b2, fp16 3-product.  grid (64, 2).
// ---------------------------------------------------------------------------
__global__ __launch_bounds__(256, 2)
void gemm2_fix_kernel(const _Float16* __restrict__ AH, const _Float16* __restrict__ AL,
                      const _Float16* __restrict__ BH, const _Float16* __restrict__ BL,
                      const float* __restrict__ bias,
                      _Float16* __restrict__ CH, _Float16* __restrict__ CL,
                      const int* __restrict__ cnt)
{
    __shared__ _Float16 lds[2][4][4096];
    const int n = *cnt;
    const int ntp = (n + 127) >> 7;
    if ((int)blockIdx.x >= ntp) return;

    const int tid  = threadIdx.x;
    const int lane = tid & 63;
    const int w    = tid >> 6;
    const int wm = w >> 1, wn = w & 1;
    const int kq = lane >> 4, lm = lane & 15;
    const int m0 = blockIdx.x * 128;
    const int n0 = blockIdx.y * 128;

    const _Float16* Ah = AH + ((size_t)blockIdx.x * 16) * 4096;
    const _Float16* Al = AL + ((size_t)blockIdx.x * 16) * 4096;
    const _Float16* Bh = BH + ((size_t)blockIdx.y * 16) * 4096;
    const _Float16* Bl = BL + ((size_t)blockIdx.y * 16) * 4096;

    f32x4 acc[4][4] = {};

    stage_panel(Ah, &lds[0][0][0], w, lane);
    stage_panel(Al, &lds[0][1][0], w, lane);
    stage_panel(Bh, &lds[0][2][0], w, lane);
    stage_panel(Bl, &lds[0][3][0], w, lane);

    constexpr int NSTEP = D_HID / 32;
    for (int t = 0; t < NSTEP; ++t) {
        const int cur = t & 1, nxt = cur ^ 1;
        __syncthreads();
        if (t + 1 < NSTEP) {
            stage_panel(Ah + (size_t)(t + 1) * 4096, &lds[nxt][0][0], w, lane);
            stage_panel(Al + (size_t)(t + 1) * 4096, &lds[nxt][1][0], w, lane);
            stage_panel(Bh + (size_t)(t + 1) * 4096, &lds[nxt][2][0], w, lane);
            stage_panel(Bl + (size_t)(t + 1) * 4096, &lds[nxt][3][0], w, lane);
        }
        mfma_tile3(&lds[cur][0][0], &lds[cur][1][0], &lds[cur][2][0], &lds[cur][3][0],
                   wm, wn, kq, lm, acc);
    }

    #pragma unroll
    for (int fn = 0; fn < 4; ++fn) {
        const int col = n0 + wn * 64 + fn * 16 + lm;
        const float bv = bias[col];
        #pragma unroll
        for (int fm = 0; fm < 4; ++fm) {
            #pragma unroll
            for (int r = 0; r < 4; ++r) {
                const int row = m0 + wm * 64 + fm * 16 + kq * 4 + r;
                const float v = acc[fm][fn][r] + bv;
                const _Float16 hi = (_Float16)v;
                const size_t idx = (((size_t)(row >> 7) * 8 + (col >> 5)) * 512
                    + (size_t)((col >> 3) & 3) * 128 + (row & 127)) * 8 + (col & 7);
                CH[idx] = hi;
                CL[idx] = (_Float16)(v - (float)hi);
            }
        }
    }
}

// ---------------------------------------------------------------------------
// dist_fix: 3-product dots on flagged rows; overwrite outIdx; flag gap<TAU2
// rows (actual row ids) into list2 for exact tier-2.  grid 64.
// ---------------------------------------------------------------------------
__global__ __launch_bounds__(256, 2)
void dist_fix_kernel(const _Float16* __restrict__ AH, const _Float16* __restrict__ AL,
                     const _Float16* __restrict__ BH, const _Float16* __restrict__ BL,
                     const float* __restrict__ cbn,
                     const int* __restrict__ list, const int* __restrict__ cnt,
                     float* __restrict__ outIdx,
                     int* __restrict__ cnt2, int* __restrict__ list2)
{
    __shared__ _Float16 lds[2][4][4096];
    const int n = *cnt;
    const int ntp = (n + 127) >> 7;
    if ((int)blockIdx.x >= ntp) return;

    const int tid  = threadIdx.x;
    const int lane = tid & 63;
    const int w    = tid >> 6;
    const int wm = w >> 1, wn = w & 1;
    const int kq = lane >> 4, lm = lane & 15;
    const int m0 = blockIdx.x * 128;

    float cbn_l[4];
    #pragma unroll
    for (int fn = 0; fn < 4; ++fn) cbn_l[fn] = cbn[wn * 64 + fn * 16 + lm];

    const _Float16* Ah = AH + ((size_t)blockIdx.x * 8) * 4096;
    const _Float16* Al = AL + ((size_t)blockIdx.x * 8) * 4096;

    f32x4 acc[4][4] = {};

    stage_panel(Ah, &lds[0][0][0], w, lane);
    stage_panel(Al, &lds[0][1][0], w, lane);
    stage_panel(BH, &lds[0][2][0], w, lane);
    stage_panel(BL, &lds[0][3][0], w, lane);

    constexpr int NSTEP = D_CODE_ / 32;
    for (int t = 0; t < NSTEP; ++t) {
        const int cur = t & 1, nxt = cur ^ 1;
        __syncthreads();
        if (t + 1 < NSTEP) {
            stage_panel(Ah + (size_t)(t + 1) * 4096, &lds[nxt][0][0], w, lane);
            stage_panel(Al + (size_t)(t + 1) * 4096, &lds[nxt][1][0], w, lane);
            stage_panel(BH + (size_t)(t + 1) * 4096, &lds[nxt][2][0], w, lane);
            stage_panel(BL + (size_t)(t + 1) * 4096, &lds[nxt][3][0], w, lane);
        }
        mfma_tile3(&lds[cur][0][0], &lds[cur][1][0], &lds[cur][2][0], &lds[cur][3][0],
                   wm, wn, kq, lm, acc);
    }

    __syncthreads();
    float* eb1 = (float*)&lds[0][0][0];
    float* eb2 = eb1 + 256;
    int*   eix = (int*)(eb2 + 256);

    #pragma unroll
    for (int fm = 0; fm < 4; ++fm) {
        #pragma unroll
        for (int r = 0; r < 4; ++r) {
            float b1v = 3.4e38f, b2v = 3.4e38f; int bi = 0;
            #pragma unroll
            for (int fn = 0; fn < 4; ++fn) {
                const float v = fmaf(-2.0f, acc[fm][fn][r], cbn_l[fn]);
                if (v < b1v) { b2v = b1v; b1v = v; bi = wn * 64 + fn * 16 + lm; }
                else if (v < b2v) b2v = v;
            }
            #pragma unroll
            for (int mk = 1; mk <= 8; mk <<= 1) {
                const float o1 = __shfl_xor(b1v, mk);
                const float o2 = __shfl_xor(b2v, mk);
                const int   oi = __shfl_xor(bi,  mk);
                if (o1 < b1v || (o1 == b1v && oi < bi)) { b2v = fminf(b1v, o2); b1v = o1; bi = oi; }
                else b2v = fminf(b2v, o1);
            }
            const int rl = wm * 64 + fm * 16 + kq * 4 + r;
            if (lm == 0) { eb1[wn * 128 + rl] = b1v; eb2[wn * 128 + rl] = b2v; eix[wn * 128 + rl] = bi; }
        }
    }
    __syncthreads();

    if (tid < 128) {
        const int slot = m0 + tid;
        if (slot < n) {
            const int rl = tid;
            const float a1 = eb1[rl], a2 = eb2[rl]; const int ai = eix[rl];
            const float o1 = eb1[128 + rl], o2 = eb2[128 + rl]; const int oi = eix[128 + rl];
            float B1, B2; int BI;
            if (o1 < a1 || (o1 == a1 && oi < ai)) { B1 = o1; BI = oi; B2 = fminf(a1, o2); }
            else                                  { B1 = a1; BI = ai; B2 = fminf(a2, o1); }
            const int row = list[slot];
            outIdx[row] = (float)BI;
            if (B2 - B1 < TAU2_GAP) {
                const int p = atomicAdd(cnt2, 1);
                if (p < 8192) list2[p] = row;
            }
        }
    }
}

// ---------------------------------------------------------------------------
// fixup2 (tier-2): exact fp32 recompute of the few near-tie rows (v6 engine).
// ---------------------------------------------------------------------------
__global__ __launch_bounds__(256)
void fixup2_kernel(const float* __restrict__ x, const float* __restrict__ W1,
                   const float* __restrict__ b1, const float* __restrict__ W2,
                   const float* __restrict__ b2, const float* __restrict__ cbT,
                   const float* __restrict__ cbnorm,
                   const int* __restrict__ cnt2, const int* __restrict__ list2,
                   float* __restrict__ outIdx)
{
    __shared__ float xr[8][1024];
    __shared__ float hr[8][512];
    __shared__ float er[8][256];
    __shared__ float dv[8][128];
    __shared__ int   di[8][128];

    const int tid  = threadIdx.x;
    const int lane = tid & 63;
    const int n = *cnt2;
    const int ngroups = (n + 7) >> 3;

    for (int g = blockIdx.x; g < ngroups; g += gridDim.x) {
        const int base = g * 8;
        const int nr = (n - base < 8) ? (n - base) : 8;
        __syncthreads();
        #pragma unroll
        for (int r = 0; r < 8; ++r) {
            if (r < nr) {
                const int row = list2[base + r];
                *(float4*)&xr[r][tid * 4] =
                    *(const float4*)(x + (size_t)row * D_INK + tid * 4);
            }
        }
        __syncthreads();

        {
            const int c2 = tid * 2;
            f32x2 a01[8] = {};
            for (int k0 = 0; k0 < D_INK; k0 += 64) {
                float xreg[8];
                #pragma unroll
                for (int r = 0; r < 8; ++r) xreg[r] = xr[r][k0 + lane];
                #pragma unroll
                for (int kb = 0; kb < 64; kb += 8) {
                    f32x2 wv[8];
                    #pragma unroll
                    for (int p = 0; p < 8; ++p)
                        wv[p] = *(const f32x2*)&W1[(size_t)(k0 + kb + p) * D_HID + c2];
                    #pragma unroll
                    for (int p = 0; p < 8; ++p) {
                        const int kk = kb + p;
                        #pragma unroll
                        for (int r = 0; r < 8; ++r) {
                            const float xb = rdlane(xreg[r], kk);
                            a01[r] = __builtin_elementwise_fma((f32x2){xb, xb}, wv[p], a01[r]);
                        }
                    }
                }
            }
            #pragma unroll
            for (int r = 0; r < 8; ++r) {
                hr[r][c2]     = fmaxf(a01[r].x + b1[c2], 0.0f);
                hr[r][c2 + 1] = fmaxf(a01[r].y + b1[c2 + 1], 0.0f);
            }
        }
        __syncthreads();

        {
            const int cc = (tid & 127) * 2;
            const int half = tid >> 7;
            f32x2 a2[4] = {};
            for (int k0 = 0; k0 < D_HID; k0 += 64) {
                float hreg[4];
                #pragma unroll
                for (int q = 0; q < 4; ++q) hreg[q] = hr[half * 4 + q][k0 + lane];
                #pragma unroll
                for (int kb = 0; kb < 64; kb += 8) {
                    f32x2 wv[8];
                    #pragma unroll
                    for (int p = 0; p < 8; ++p)
                        wv[p] = *(const f32x2*)&W2[(size_t)(k0 + kb + p) * D_CODE_ + cc];
                    #pragma unroll
                    for (int p = 0; p < 8; ++p) {
                        const int kk = kb + p;
                        #pragma unroll
                        for (int q = 0; q < 4; ++q) {
                            const float hb = rdlane(hreg[q], kk);
                            a2[q] = __builtin_elementwise_fma((f32x2){hb, hb}, wv[p], a2[q]);
                        }
                    }
                }
            }
            #pragma unroll
            for (int q = 0; q < 4; ++q) {
                er[half * 4 + q][cc]     = a2[q].x + b2[cc];
                er[half * 4 + q][cc + 1] = a2[q].y + b2[cc + 1];
            }
        }
        __syncthreads();

        {
            const int j = tid & 127;
            const int half = tid >> 7;
            float e2[4], dt[4];
            #pragma unroll
            for (int q = 0; q < 4; ++q) { e2[q] = 0.0f; dt[q] = 0.0f; }
            for (int k0 = 0; k0 < D_CODE_; k0 += 64) {
                float ereg[4];
                #pragma unroll
                for (int q = 0; q < 4; ++q) ereg[q] = er[half * 4 + q][k0 + lane];
                #pragma unroll
                for (int kb = 0; kb < 64; kb += 8) {
                    float cv[8];
                    #pragma unroll
                    for (int p = 0; p < 8; ++p)
                        cv[p] = cbT[(size_t)(k0 + kb + p) * N_CODES_ + j];
                    #pragma unroll
                    for (int p = 0; p < 8; ++p) {
                        const int kk = kb + p;
                        #pragma unroll
                        for (int q = 0; q < 4; ++q) {
                            const float ev = rdlane(ereg[q], kk);
                            e2[q] = fmaf(ev, ev, e2[q]);
                            dt[q] = fmaf(ev, cv[p], dt[q]);
                        }
                    }
                }
            }
            #pragma unroll
            for (int q = 0; q < 4; ++q) {
                dv[half * 4 + q][j] = (e2[q] - 2.0f * dt[q]) + cbnorm[j];
                di[half * 4 + q][j] = j;
            }
        }
        __syncthreads();

        #pragma unroll
        for (int pass = 0; pass < 4; ++pass) {
            const int r = pass * 2 + (tid >> 7);
            const int i = tid & 127;
            for (int st = 64; st >= 1; st >>= 1) {
                if (i < st) {
                    const float a = dv[r][i], b = dv[r][i + st];
                    const int  ib = di[r][i + st];
                    if (b < a || (b == a && ib < di[r][i])) { dv[r][i] = b; di[r][i] = ib; }
                }
                __syncthreads();
            }
        }
        if (tid < nr) outIdx[list2[base + tid]] = (float)di[tid][0];
    }
}

// ---------------------------------------------------------------------------
__global__ void finalize_kernel(const float* __restrict__ accum, float* __restrict__ out)
{
    const float inv = 1.0f / (32768.0f * 256.0f);
    const float loss = (accum[0] + accum[1]) * inv;   // commitment == codebook
    out[32768] = loss;
    out[32769] = loss;
    out[32770] = 1.25f * loss;
}

// ---------------------------------------------------------------------------
extern "C" void kernel_launch(void* const* d_in, const int* in_sizes, int n_in,
                              void* d_out, int out_size, void* d_ws, size_t ws_size,
                              hipStream_t stream)
{
    (void)in_sizes; (void)n_in; (void)out_size; (void)ws_size;

    const float* x  = (const float*)d_in[0];  // [32768,1024]
    const float* W1 = (const float*)d_in[1];  // [1024,512]
    const float* b1 = (const float*)d_in[2];  // [512]
    const float* W2 = (const float*)d_in[3];  // [512,256]
    const float* b2 = (const float*)d_in[4];  // [256]
    const float* cb = (const float*)d_in[5];  // [128,256]
    float* out = (float*)d_out;

    // workspace layout (bytes):
    //  [0,4MB): weights/codebook panels + small buffers
    //  [4MB,68MB): xP (main); encP overlays first 16MB; xfP overlays [20,52)MB
    //  [68MB,100MB): hP (main); hfP/encfP overlay after gemm2
    char* ws = (char*)d_ws;
    _Float16* W1P   = (_Float16*)(ws + 0);                       // 1 MB
    _Float16* W1Pl  = (_Float16*)(ws + (1u<<20));                // 1 MB
    _Float16* W2P   = (_Float16*)(ws + (2u<<20));                // 256 KB
    _Float16* W2Pl  = (_Float16*)(ws + (2u<<20) + 262144);       // 256 KB
    _Float16* cbP   = (_Float16*)(ws + (2u<<20) + 524288);       // 64 KB
    _Float16* cbPl  = (_Float16*)(ws + (2u<<20) + 589824);       // 64 KB
    float*    cbT   = (float*   )(ws + (2u<<20) + 655360);       // 128 KB
    float*    cbn   = (float*   )(ws + (2u<<20) + 786432);       // 512 B
    float*    accum = (float*   )(ws + (2u<<20) + 786944);       // 64 B
    int*      cnt   = (int*     )(ws + (2u<<20) + 787008);       // 64 B
    int*      cnt2  = (int*     )(ws + (2u<<20) + 787072);       // 64 B
    int*      list  = (int*     )(ws + (2u<<20) + 787136);       // 128 KB
    int*      list2 = (int*     )(ws + (2u<<20) + 918208);       // 32 KB

    _Float16* xP    = (_Float16*)(ws + (size_t)(4u<<20));                    // 64 MB
    _Float16* encP  = (_Float16*)(ws + (size_t)(4u<<20));                    // 16 MB (xP reuse)
    _Float16* xfPh  = (_Float16*)(ws + (size_t)(4u<<20) + 16777216);         // 16 MB (xP reuse)
    _Float16* xfPl  = (_Float16*)(ws + (size_t)(4u<<20) + 33554432);         // 16 MB (xP reuse)
    _Float16* hP    = (_Float16*)(ws + (size_t)(68u<<20));                   // 32 MB
    _Float16* hfPh  = (_Float16*)(ws + (size_t)(68u<<20));                   //  8 MB (hP reuse)
    _Float16* hfPl  = (_Float16*)(ws + (size_t)(68u<<20) + 8388608);         //  8 MB
    _Float16* encfPh= (_Float16*)(ws + (size_t)(68u<<20) + 16777216);        //  4 MB
    _Float16* encfPl= (_Float16*)(ws + (size_t)(68u<<20) + 20971520);        //  4 MB

    prep_cb_kernel<<<N_CODES_, 256, 0, stream>>>(cb, cbP, cbPl, cbT, cbn, accum, cnt, cnt2);
    pack_w_kernel<<<dim3(D_INK / 32, D_HID / 128), 256, 0, stream>>>(W1, W1P, W1Pl, D_INK, D_HID);
    pack_w_kernel<<<dim3(D_HID / 32, D_CODE_ / 128), 256, 0, stream>>>(W2, W2P, W2Pl, D_HID, D_CODE_);
    pack_x_kernel<<<dim3(M_ROWS / 128, D_INK / 128), 256, 0, stream>>>(x, xP);

    gemm1_kernel<<<(M_ROWS / 128) * (D_HID / 128), 256, 0, stream>>>(xP, W1P, b1, hP);
    gemm2_kernel<<<(M_ROWS / 128) * (D_CODE_ / 128), 256, 0, stream>>>(hP, W2P, b2, encP, accum);
    dist_kernel<<<M_ROWS / 128, 256, 0, stream>>>(encP, cbP, cbn, out, accum, cnt, list);

    // tier-1: accurate fp16x3 recompute of flagged rows (MFMA pipe)
    gather_pack_fix_kernel<<<dim3(128, 8), 256, 0, stream>>>(x, list, cnt, xfPh, xfPl);
    gemm1_fix_kernel<<<dim3(64, 4), 256, 0, stream>>>(xfPh, xfPl, W1P, W1Pl, b1, hfPh, hfPl, cnt);
    gemm2_fix_kernel<<<dim3(64, 2), 256, 0, stream>>>(hfPh, hfPl, W2P, W2Pl, b2, encfPh, encfPl, cnt);
    dist_fix_kernel<<<64, 256, 0, stream>>>(encfPh, encfPl, cbP, cbPl, cbn,
                                            list, cnt, out, cnt2, list2);
    // tier-2: exact fp32 for residual near-ties (few rows)
    fixup2_kernel<<<64, 256, 0, stream>>>(x, W1, b1, W2, b2, cbT, cbn, cnt2, list2, out);
    finalize_kernel<<<1, 1, 0, stream>>>(accum, out);
}

// Round 18
// 268.974 us; speedup vs baseline: 1.1448x; 1.1448x over previous
//
#include <hip/hip_runtime.h>
#include <cstddef>
#include <cstdint>

// Problem constants
static constexpr int M_ROWS  = 32768;   // B*T
static constexpr int D_INK   = 1024;
static constexpr int D_HID   = 512;
static constexpr int D_CODE_ = 256;
static constexpr int N_CODES_= 128;

// fp16 single-product pairwise-d2 gap jitter sigma ~= 0.023 -> TAU = 6.5 sigma
static constexpr float TAU_GAP = 0.15f;
// fp16 3-product jitter sigma ~= 5e-4 -> TAU2 = 10 sigma
static constexpr float TAU2_GAP = 0.005f;

using f16x8 = __attribute__((ext_vector_type(8))) _Float16;
using f32x4 = __attribute__((ext_vector_type(4))) float;
using f32x2 = __attribute__((ext_vector_type(2))) float;

__device__ __forceinline__ float rdlane(float v, int kk) {
    return __uint_as_float(__builtin_amdgcn_readlane(__float_as_uint(v), kk));
}

// ---------------------------------------------------------------------------
// Packed panel format: one panel = one (128-row tile) x (32-k step):
//   panel[(kq*128 + rc)*8 + j] = src[tile*128 + rc][ks*32 + kq*8 + j]
// ---------------------------------------------------------------------------

__device__ __forceinline__ void dma16(const void* g, void* l) {
    __builtin_amdgcn_global_load_lds(
        (const __attribute__((address_space(1))) void*)g,
        (__attribute__((address_space(3))) void*)l, 16, 0, 0);
}

// stage one 8 KB panel into LDS: 8 dma16 instrs, 2 per wave, lane-contiguous
__device__ __forceinline__ void stage_panel(const _Float16* __restrict__ p,
                                            _Float16* dst, int w, int lane)
{
    #pragma unroll
    for (int ii = 0; ii < 2; ++ii) {
        const int I = 2 * w + ii;           // 0..7 (wave-uniform)
        dma16(p + (size_t)I * 512 + lane * 8, dst + (size_t)I * 512);
    }
}

// one BK=32 compute step: 4x4 fragment tile per wave, single fp16 product
__device__ __forceinline__ void mfma_tile(const _Float16* sA, const _Float16* sB,
                                          int wm, int wn, int kq, int lm,
                                          f32x4 (&acc)[4][4])
{
    f16x8 a[4];
    #pragma unroll
    for (int fm = 0; fm < 4; ++fm)
        a[fm] = *(const f16x8*)(sA + (kq * 128 + wm * 64 + fm * 16 + lm) * 8);
    #pragma unroll
    for (int fn = 0; fn < 4; ++fn) {
        const f16x8 b = *(const f16x8*)(sB + (kq * 128 + wn * 64 + fn * 16 + lm) * 8);
        #pragma unroll
        for (int fm = 0; fm < 4; ++fm)
            acc[fm][fn] = __builtin_amdgcn_mfma_f32_16x16x32_f16(a[fm], b, acc[fm][fn], 0, 0, 0);
    }
}

// 3-product hi/lo step (~fp32 accuracy): ah*bh + al*bh + ah*bl
__device__ __forceinline__ void mfma_tile3(const _Float16* sAh, const _Float16* sAl,
                                           const _Float16* sBh, const _Float16* sBl,
                                           int wm, int wn, int kq, int lm,
                                           f32x4 (&acc)[4][4])
{
    f16x8 ah[4], al[4];
    #pragma unroll
    for (int fm = 0; fm < 4; ++fm) {
        const int fA = kq * 128 + wm * 64 + fm * 16 + lm;
        ah[fm] = *(const f16x8*)(sAh + fA * 8);
        al[fm] = *(const f16x8*)(sAl + fA * 8);
    }
    #pragma unroll
    for (int fn = 0; fn < 4; ++fn) {
        const int fB = kq * 128 + wn * 64 + fn * 16 + lm;
        const f16x8 bh = *(const f16x8*)(sBh + fB * 8);
        const f16x8 bl = *(const f16x8*)(sBl + fB * 8);
        #pragma unroll
        for (int fm = 0; fm < 4; ++fm) {
            acc[fm][fn] = __builtin_amdgcn_mfma_f32_16x16x32_f16(ah[fm], bh, acc[fm][fn], 0, 0, 0);
            acc[fm][fn] = __builtin_amdgcn_mfma_f32_16x16x32_f16(al[fm], bh, acc[fm][fn], 0, 0, 0);
            acc[fm][fn] = __builtin_amdgcn_mfma_f32_16x16x32_f16(ah[fm], bl, acc[fm][fn], 0, 0, 0);
        }
    }
}

// bijective XCD swizzle (nwg % 8 == 0)
__device__ __forceinline__ int xcd_swz(int bid, int nwg) {
    const int q = nwg >> 3;
    return (bid & 7) * q + (bid >> 3);
}

// ---------------------------------------------------------------------------
// prep: codebook -> packed fp16 hi/lo panels + fp32 transposed copy,
// exact per-code norms, zero accums/counters.
// ---------------------------------------------------------------------------
__global__ __launch_bounds__(256)
void prep_cb_kernel(const float* __restrict__ cb, _Float16* __restrict__ cbP,
                    _Float16* __restrict__ cbPl, float* __restrict__ cbT,
                    float* __restrict__ cbnorm, float* __restrict__ accum,
                    int* __restrict__ cnt, int* __restrict__ cnt2)
{
    const int j = blockIdx.x;      // code 0..127
    const int t = threadIdx.x;     // dim 0..255
    const float v = cb[j * D_CODE_ + t];
    const int ks = t >> 5, kq = (t >> 3) & 3, jj = t & 7;
    const _Float16 hi = (_Float16)v;
    cbP [((size_t)ks * 512 + kq * 128 + j) * 8 + jj] = hi;
    cbPl[((size_t)ks * 512 + kq * 128 + j) * 8 + jj] = (_Float16)(v - (float)hi);
    cbT[(size_t)t * N_CODES_ + j] = v;

    __shared__ float sr[256];
    sr[t] = v * v;
    __syncthreads();
    for (int s = 128; s >= 1; s >>= 1) {
        if (t < s) sr[t] += sr[t + s];
        __syncthreads();
    }
    if (t == 0) cbnorm[j] = sr[0];
    if (j == 0 && t < 2) accum[t] = 0.0f;
    if (j == 0 && t == 2) *cnt = 0;
    if (j == 0 && t == 3) *cnt2 = 0;
}

// ---------------------------------------------------------------------------
// pack_w: W [K][N] fp32 -> hi AND lo fp16 B-side panels.
// ---------------------------------------------------------------------------
__global__ __launch_bounds__(256)
void pack_w_kernel(const float* __restrict__ W, _Float16* __restrict__ WPh,
                   _Float16* __restrict__ WPl, int Kd, int Nd)
{
    const int ks = blockIdx.x, nt = blockIdx.y;
    const int t = threadIdx.x;
    const size_t pbase = ((size_t)nt * (Kd >> 5) + ks) * 4096;
    #pragma unroll
    for (int half = 0; half < 2; ++half) {
        const int f = half * 256 + t;
        const int nc = f & 127, kq = f >> 7;
        f16x8 vh, vl;
        #pragma unroll
        for (int j = 0; j < 8; ++j) {
            const float w = W[(size_t)(ks * 32 + kq * 8 + j) * Nd + nt * 128 + nc];
            const _Float16 hi = (_Float16)w;
            vh[j] = hi;
            vl[j] = (_Float16)(w - (float)hi);
        }
        *(f16x8*)(WPh + pbase + (size_t)f * 8) = vh;
        *(f16x8*)(WPl + pbase + (size_t)f * 8) = vl;
    }
}

// ---------------------------------------------------------------------------
// pack_x: x fp32 [M][1024] -> A-side fp16 panels (main path, hi only).
// ---------------------------------------------------------------------------
__global__ __launch_bounds__(256)
void pack_x_kernel(const float* __restrict__ X, _Float16* __restrict__ XP)
{
    __shared__ _Float16 sh[128][136];
    const int t  = threadIdx.x;
    const int mt = blockIdx.x;
    const int kc = blockIdx.y;

    const float* src = X + (size_t)mt * 128 * D_INK + kc * 128;
    #pragma unroll
    for (int i = 0; i < 16; ++i) {
        const int idx = i * 256 + t;
        const int row = idx >> 5, c4 = idx & 31;
        const float4 v = *(const float4*)(src + (size_t)row * D_INK + c4 * 4);
        _Float16* d = &sh[row][c4 * 4];
        d[0] = (_Float16)v.x; d[1] = (_Float16)v.y;
        d[2] = (_Float16)v.z; d[3] = (_Float16)v.w;
    }
    __syncthreads();

    _Float16* dst = XP + ((size_t)mt * 32 + kc * 4) * 4096;
    #pragma unroll
    for (int s = 0; s < 4; ++s) {
        #pragma unroll
        for (int half = 0; half < 2; ++half) {
            const int f = half * 256 + t;
            const int rc = f & 127, kq = f >> 7;
            const f16x8 v = *(const f16x8*)(&sh[rc][s * 32 + kq * 8]);
            *(f16x8*)(dst + (size_t)s * 4096 + (size_t)f * 8) = v;
        }
    }
}

// ---------------------------------------------------------------------------
// GEMM1 (main): h = relu(x @ W1 + b1).
// ---------------------------------------------------------------------------
__global__ __launch_bounds__(256, 4)
void gemm1_kernel(const _Float16* __restrict__ AP, const _Float16* __restrict__ BP,
                  const float* __restrict__ bias, _Float16* __restrict__ CP)
{
    __shared__ _Float16 lds[2][2][4096];

    const int tid  = threadIdx.x;
    const int lane = tid & 63;
    const int w    = tid >> 6;
    const int wm = w >> 1, wn = w & 1;
    const int kq = lane >> 4, lm = lane & 15;

    const int swz = xcd_swz(blockIdx.x, (M_ROWS / 128) * (D_HID / 128));
    const int n0 = (swz & 3) * 128;
    const int m0 = (swz >> 2) * 128;

    const _Float16* Apan = AP + ((size_t)(m0 >> 7) * 32) * 4096;
    const _Float16* Bpan = BP + ((size_t)(n0 >> 7) * 32) * 4096;

    f32x4 acc[4][4] = {};

    stage_panel(Apan, &lds[0][0][0], w, lane);
    stage_panel(Bpan, &lds[0][1][0], w, lane);

    constexpr int NSTEP = D_INK / 32;
    for (int t = 0; t < NSTEP; ++t) {
        const int cur = t & 1, nxt = cur ^ 1;
        __syncthreads();
        if (t + 1 < NSTEP) {
            stage_panel(Apan + (size_t)(t + 1) * 4096, &lds[nxt][0][0], w, lane);
            stage_panel(Bpan + (size_t)(t + 1) * 4096, &lds[nxt][1][0], w, lane);
        }
        mfma_tile(&lds[cur][0][0], &lds[cur][1][0], wm, wn, kq, lm, acc);
    }

    #pragma unroll
    for (int fn = 0; fn < 4; ++fn) {
        const int col = n0 + wn * 64 + fn * 16 + lm;
        const float bv = bias[col];
        #pragma unroll
        for (int fm = 0; fm < 4; ++fm) {
            #pragma unroll
            for (int r = 0; r < 4; ++r) {
                const int row = m0 + wm * 64 + fm * 16 + kq * 4 + r;
                const float v = fmaxf(acc[fm][fn][r] + bv, 0.0f);
                CP[(((size_t)(row >> 7) * 16 + (col >> 5)) * 512
                    + (size_t)((col >> 3) & 3) * 128 + (row & 127)) * 8 + (col & 7)]
                    = (_Float16)v;
            }
        }
    }
}

// ---------------------------------------------------------------------------
// GEMM2 (main): enc = h @ W2 + b2 (+ sum(enc^2) atomic).
// ---------------------------------------------------------------------------
__global__ __launch_bounds__(256, 4)
void gemm2_kernel(const _Float16* __restrict__ AP, const _Float16* __restrict__ BP,
                  const float* __restrict__ bias, _Float16* __restrict__ CP,
                  float* __restrict__ accum)
{
    __shared__ _Float16 lds[2][2][4096];

    const int tid  = threadIdx.x;
    const int lane = tid & 63;
    const int w    = tid >> 6;
    const int wm = w >> 1, wn = w & 1;
    const int kq = lane >> 4, lm = lane & 15;

    const int swz = xcd_swz(blockIdx.x, (M_ROWS / 128) * (D_CODE_ / 128));
    const int n0 = (swz & 1) * 128;
    const int m0 = (swz >> 1) * 128;

    const _Float16* Apan = AP + ((size_t)(m0 >> 7) * 16) * 4096;
    const _Float16* Bpan = BP + ((size_t)(n0 >> 7) * 16) * 4096;

    f32x4 acc[4][4] = {};

    stage_panel(Apan, &lds[0][0][0], w, lane);
    stage_panel(Bpan, &lds[0][1][0], w, lane);

    constexpr int NSTEP = D_HID / 32;
    for (int t = 0; t < NSTEP; ++t) {
        const int cur = t & 1, nxt = cur ^ 1;
        __syncthreads();
        if (t + 1 < NSTEP) {
            stage_panel(Apan + (size_t)(t + 1) * 4096, &lds[nxt][0][0], w, lane);
            stage_panel(Bpan + (size_t)(t + 1) * 4096, &lds[nxt][1][0], w, lane);
        }
        mfma_tile(&lds[cur][0][0], &lds[cur][1][0], wm, wn, kq, lm, acc);
    }

    float sumsq = 0.0f;
    #pragma unroll
    for (int fn = 0; fn < 4; ++fn) {
        const int col = n0 + wn * 64 + fn * 16 + lm;
        const float bv = bias[col];
        #pragma unroll
        for (int fm = 0; fm < 4; ++fm) {
            #pragma unroll
            for (int r = 0; r < 4; ++r) {
                const int row = m0 + wm * 64 + fm * 16 + kq * 4 + r;
                const float v = acc[fm][fn][r] + bv;
                sumsq = fmaf(v, v, sumsq);
                CP[(((size_t)(row >> 7) * 8 + (col >> 5)) * 512
                    + (size_t)((col >> 3) & 3) * 128 + (row & 127)) * 8 + (col & 7)]
                    = (_Float16)v;
            }
        }
    }
    #pragma unroll
    for (int mk = 1; mk <= 32; mk <<= 1) sumsq += __shfl_xor(sumsq, mk);
    if (lane == 0) atomicAdd(&accum[1], sumsq);
}

// ---------------------------------------------------------------------------
// dist (main): argmin + gap flagging + min-term loss sum.
// ---------------------------------------------------------------------------
__global__ __launch_bounds__(256, 4)
void dist_kernel(const _Float16* __restrict__ AP, const _Float16* __restrict__ BP,
                 const float* __restrict__ cbn,
                 float* __restrict__ outIdx, float* __restrict__ accum,
                 int* __restrict__ cnt, int* __restrict__ list)
{
    __shared__ _Float16 lds[2][2][4096];

    const int tid  = threadIdx.x;
    const int lane = tid & 63;
    const int w    = tid >> 6;
    const int wm = w >> 1, wn = w & 1;
    const int kq = lane >> 4, lm = lane & 15;
    const int m0 = blockIdx.x * 128;

    float cbn_l[4];
    #pragma unroll
    for (int fn = 0; fn < 4; ++fn) cbn_l[fn] = cbn[wn * 64 + fn * 16 + lm];

    const _Float16* Apan = AP + ((size_t)(m0 >> 7) * 8) * 4096;

    f32x4 acc[4][4] = {};

    stage_panel(Apan, &lds[0][0][0], w, lane);
    stage_panel(BP,   &lds[0][1][0], w, lane);

    constexpr int NSTEP = D_CODE_ / 32;
    for (int t = 0; t < NSTEP; ++t) {
        const int cur = t & 1, nxt = cur ^ 1;
        __syncthreads();
        if (t + 1 < NSTEP) {
            stage_panel(Apan + (size_t)(t + 1) * 4096, &lds[nxt][0][0], w, lane);
            stage_panel(BP   + (size_t)(t + 1) * 4096, &lds[nxt][1][0], w, lane);
        }
        mfma_tile(&lds[cur][0][0], &lds[cur][1][0], wm, wn, kq, lm, acc);
    }

    __syncthreads();
    float* eb1 = (float*)&lds[0][0][0];        // [2][128]
    float* eb2 = eb1 + 256;
    int*   eix = (int*)(eb2 + 256);

    #pragma unroll
    for (int fm = 0; fm < 4; ++fm) {
        #pragma unroll
        for (int r = 0; r < 4; ++r) {
            float b1v = 3.4e38f, b2v = 3.4e38f; int bi = 0;
            #pragma unroll
            for (int fn = 0; fn < 4; ++fn) {
                const float v = fmaf(-2.0f, acc[fm][fn][r], cbn_l[fn]);
                if (v < b1v) { b2v = b1v; b1v = v; bi = wn * 64 + fn * 16 + lm; }
                else if (v < b2v) b2v = v;
            }
            #pragma unroll
            for (int mk = 1; mk <= 8; mk <<= 1) {
                const float o1 = __shfl_xor(b1v, mk);
                const float o2 = __shfl_xor(b2v, mk);
                const int   oi = __shfl_xor(bi,  mk);
                if (o1 < b1v || (o1 == b1v && oi < bi)) { b2v = fminf(b1v, o2); b1v = o1; bi = oi; }
                else b2v = fminf(b2v, o1);
            }
            const int rl = wm * 64 + fm * 16 + kq * 4 + r;
            if (lm == 0) { eb1[wn * 128 + rl] = b1v; eb2[wn * 128 + rl] = b2v; eix[wn * 128 + rl] = bi; }
        }
    }
    __syncthreads();

    if (tid < 128) {
        const int rl = tid;
        const float a1 = eb1[rl], a2 = eb2[rl]; const int ai = eix[rl];
        const float o1 = eb1[128 + rl], o2 = eb2[128 + rl]; const int oi = eix[128 + rl];
        float B1, B2; int BI;
        if (o1 < a1 || (o1 == a1 && oi < ai)) { B1 = o1; BI = oi; B2 = fminf(a1, o2); }
        else                                  { B1 = a1; BI = ai; B2 = fminf(a2, o1); }
        outIdx[m0 + rl] = (float)BI;
        if (B2 - B1 < TAU_GAP) {
            const int p = atomicAdd(cnt, 1);
            if (p < 32768) list[p] = m0 + rl;
        }
        float s = B1;
        #pragma unroll
        for (int mk = 1; mk <= 32; mk <<= 1) s += __shfl_xor(s, mk);
        if (lane == 0) atomicAdd(&accum[0], s);
    }
}

// ---------------------------------------------------------------------------
// gather_pack_fix: flagged x rows -> hi/lo fp16 A-side panels (padded with
// row list[n-1]).  grid (128, 8): half-tile of 64 rows x 128-k chunk.
// ---------------------------------------------------------------------------
__global__ __launch_bounds__(256)
void gather_pack_fix_kernel(const float* __restrict__ X,
                            const int* __restrict__ list, const int* __restrict__ cnt,
                            _Float16* __restrict__ XH, _Float16* __restrict__ XL)
{
    __shared__ _Float16 shh[64][136];
    __shared__ _Float16 shl[64][136];
    const int n = *cnt;
    if (n == 0) return;
    const int ntp = (n + 127) >> 7;
    const int ht = blockIdx.x;
    if (ht >= ntp * 2) return;
    const int kc = blockIdx.y;
    const int t = threadIdx.x;

    #pragma unroll
    for (int i = 0; i < 8; ++i) {
        const int idx = i * 256 + t;
        const int rl = idx >> 5;
        const int c4 = idx & 31;
        const int slot = ht * 64 + rl;
        const int srcrow = list[slot < n ? slot : n - 1];
        const float4 v = *(const float4*)(X + (size_t)srcrow * D_INK + kc * 128 + c4 * 4);
        _Float16* dh = &shh[rl][c4 * 4];
        _Float16* dl = &shl[rl][c4 * 4];
        const float vv[4] = {v.x, v.y, v.z, v.w};
        #pragma unroll
        for (int q = 0; q < 4; ++q) {
            const _Float16 hi = (_Float16)vv[q];
            dh[q] = hi;
            dl[q] = (_Float16)(vv[q] - (float)hi);
        }
    }
    __syncthreads();

    const int rl = t & 63, kq = t >> 6;
    const int rc = (ht & 1) * 64 + rl;
    const size_t pb = ((size_t)(ht >> 1) * 32 + kc * 4) * 4096;
    #pragma unroll
    for (int s = 0; s < 4; ++s) {
        const size_t off = pb + (size_t)s * 4096 + (size_t)(kq * 128 + rc) * 8;
        *(f16x8*)(XH + off) = *(const f16x8*)(&shh[rl][s * 32 + kq * 8]);
        *(f16x8*)(XL + off) = *(const f16x8*)(&shl[rl][s * 32 + kq * 8]);
    }
}

// ---------------------------------------------------------------------------
// gemm1_fix: h_fix(hi/lo) = relu(x_fix @ W1 + b1), fp16 3-product MFMA.
// ---------------------------------------------------------------------------
__global__ __launch_bounds__(256, 2)
void gemm1_fix_kernel(const _Float16* __restrict__ AH, const _Float16* __restrict__ AL,
                      const _Float16* __restrict__ BH, const _Float16* __restrict__ BL,
                      const float* __restrict__ bias,
                      _Float16* __restrict__ CH, _Float16* __restrict__ CL,
                      const int* __restrict__ cnt)
{
    __shared__ _Float16 lds[2][4][4096];   // 64 KB
    const int n = *cnt;
    const int ntp = (n + 127) >> 7;
    if ((int)blockIdx.x >= ntp) return;

    const int tid  = threadIdx.x;
    const int lane = tid & 63;
    const int w    = tid >> 6;
    const int wm = w >> 1, wn = w & 1;
    const int kq = lane >> 4, lm = lane & 15;
    const int m0 = blockIdx.x * 128;
    const int n0 = blockIdx.y * 128;

    const _Float16* Ah = AH + ((size_t)blockIdx.x * 32) * 4096;
    const _Float16* Al = AL + ((size_t)blockIdx.x * 32) * 4096;
    const _Float16* Bh = BH + ((size_t)blockIdx.y * 32) * 4096;
    const _Float16* Bl = BL + ((size_t)blockIdx.y * 32) * 4096;

    f32x4 acc[4][4] = {};

    stage_panel(Ah, &lds[0][0][0], w, lane);
    stage_panel(Al, &lds[0][1][0], w, lane);
    stage_panel(Bh, &lds[0][2][0], w, lane);
    stage_panel(Bl, &lds[0][3][0], w, lane);

    constexpr int NSTEP = D_INK / 32;
    for (int t = 0; t < NSTEP; ++t) {
        const int cur = t & 1, nxt = cur ^ 1;
        __syncthreads();
        if (t + 1 < NSTEP) {
            stage_panel(Ah + (size_t)(t + 1) * 4096, &lds[nxt][0][0], w, lane);
            stage_panel(Al + (size_t)(t + 1) * 4096, &lds[nxt][1][0], w, lane);
            stage_panel(Bh + (size_t)(t + 1) * 4096, &lds[nxt][2][0], w, lane);
            stage_panel(Bl + (size_t)(t + 1) * 4096, &lds[nxt][3][0], w, lane);
        }
        mfma_tile3(&lds[cur][0][0], &lds[cur][1][0], &lds[cur][2][0], &lds[cur][3][0],
                   wm, wn, kq, lm, acc);
    }

    #pragma unroll
    for (int fn = 0; fn < 4; ++fn) {
        const int col = n0 + wn * 64 + fn * 16 + lm;
        const float bv = bias[col];
        #pragma unroll
        for (int fm = 0; fm < 4; ++fm) {
            #pragma unroll
            for (int r = 0; r < 4; ++r) {
                const int row = m0 + wm * 64 + fm * 16 + kq * 4 + r;
                const float v = fmaxf(acc[fm][fn][r] + bv, 0.0f);
                const _Float16 hi = (_Float16)v;
                const size_t idx = (((size_t)(row >> 7) * 16 + (col >> 5)) * 512
                    + (size_t)((col >> 3) & 3) * 128 + (row & 127)) * 8 + (col & 7);
                CH[idx] = hi;
                CL[idx] = (_Float16)(v - (float)hi);
            }
        }
    }
}

// ---------------------------------------------------------------------------
// gemm2_fix: enc_fix(hi/lo) = h_fix @ W2 + b2, fp16 3-product.
// ---------------------------------------------------------------------------
__global__ __launch_bounds__(256, 2)
void gemm2_fix_kernel(const _Float16* __restrict__ AH, const _Float16* __restrict__ AL,
                      const _Float16* __restrict__ BH, const _Float16* __restrict__ BL,
                      const float* __restrict__ bias,
                      _Float16* __restrict__ CH, _Float16* __restrict__ CL,
                      const int* __restrict__ cnt)
{
    __shared__ _Float16 lds[2][4][4096];
    const int n = *cnt;
    const int ntp = (n + 127) >> 7;
    if ((int)blockIdx.x >= ntp) return;

    const int tid  = threadIdx.x;
    const int lane = tid & 63;
    const int w    = tid >> 6;
    const int wm = w >> 1, wn = w & 1;
    const int kq = lane >> 4, lm = lane & 15;
    const int m0 = blockIdx.x * 128;
    const int n0 = blockIdx.y * 128;

    const _Float16* Ah = AH + ((size_t)blockIdx.x * 16) * 4096;
    const _Float16* Al = AL + ((size_t)blockIdx.x * 16) * 4096;
    const _Float16* Bh = BH + ((size_t)blockIdx.y * 16) * 4096;
    const _Float16* Bl = BL + ((size_t)blockIdx.y * 16) * 4096;

    f32x4 acc[4][4] = {};

    stage_panel(Ah, &lds[0][0][0], w, lane);
    stage_panel(Al, &lds[0][1][0], w, lane);
    stage_panel(Bh, &lds[0][2][0], w, lane);
    stage_panel(Bl, &lds[0][3][0], w, lane);

    constexpr int NSTEP = D_HID / 32;
    for (int t = 0; t < NSTEP; ++t) {
        const int cur = t & 1, nxt = cur ^ 1;
        __syncthreads();
        if (t + 1 < NSTEP) {
            stage_panel(Ah + (size_t)(t + 1) * 4096, &lds[nxt][0][0], w, lane);
            stage_panel(Al + (size_t)(t + 1) * 4096, &lds[nxt][1][0], w, lane);
            stage_panel(Bh + (size_t)(t + 1) * 4096, &lds[nxt][2][0], w, lane);
            stage_panel(Bl + (size_t)(t + 1) * 4096, &lds[nxt][3][0], w, lane);
        }
        mfma_tile3(&lds[cur][0][0], &lds[cur][1][0], &lds[cur][2][0], &lds[cur][3][0],
                   wm, wn, kq, lm, acc);
    }

    #pragma unroll
    for (int fn = 0; fn < 4; ++fn) {
        const int col = n0 + wn * 64 + fn * 16 + lm;
        const float bv = bias[col];
        #pragma unroll
        for (int fm = 0; fm < 4; ++fm) {
            #pragma unroll
            for (int r = 0; r < 4; ++r) {
                const int row = m0 + wm * 64 + fm * 16 + kq * 4 + r;
                const float v = acc[fm][fn][r] + bv;
                const _Float16 hi = (_Float16)v;
                const size_t idx = (((size_t)(row >> 7) * 8 + (col >> 5)) * 512
                    + (size_t)((col >> 3) & 3) * 128 + (row & 127)) * 8 + (col & 7);
                CH[idx] = hi;
                CL[idx] = (_Float16)(v - (float)hi);
            }
        }
    }
}

// ---------------------------------------------------------------------------
// dist_fix: 3-product dots on flagged rows; overwrite outIdx; flag gap<TAU2
// rows into list2 for exact tier-2.
// ---------------------------------------------------------------------------
__global__ __launch_bounds__(256, 2)
void dist_fix_kernel(const _Float16* __restrict__ AH, const _Float16* __restrict__ AL,
                     const _Float16* __restrict__ BH, const _Float16* __restrict__ BL,
                     const float* __restrict__ cbn,
                     const int* __restrict__ list, const int* __restrict__ cnt,
                     float* __restrict__ outIdx,
                     int* __restrict__ cnt2, int* __restrict__ list2)
{
    __shared__ _Float16 lds[2][4][4096];
    const int n = *cnt;
    const int ntp = (n + 127) >> 7;
    if ((int)blockIdx.x >= ntp) return;

    const int tid  = threadIdx.x;
    const int lane = tid & 63;
    const int w    = tid >> 6;
    const int wm = w >> 1, wn = w & 1;
    const int kq = lane >> 4, lm = lane & 15;
    const int m0 = blockIdx.x * 128;

    float cbn_l[4];
    #pragma unroll
    for (int fn = 0; fn < 4; ++fn) cbn_l[fn] = cbn[wn * 64 + fn * 16 + lm];

    const _Float16* Ah = AH + ((size_t)blockIdx.x * 8) * 4096;
    const _Float16* Al = AL + ((size_t)blockIdx.x * 8) * 4096;

    f32x4 acc[4][4] = {};

    stage_panel(Ah, &lds[0][0][0], w, lane);
    stage_panel(Al, &lds[0][1][0], w, lane);
    stage_panel(BH, &lds[0][2][0], w, lane);
    stage_panel(BL, &lds[0][3][0], w, lane);

    constexpr int NSTEP = D_CODE_ / 32;
    for (int t = 0; t < NSTEP; ++t) {
        const int cur = t & 1, nxt = cur ^ 1;
        __syncthreads();
        if (t + 1 < NSTEP) {
            stage_panel(Ah + (size_t)(t + 1) * 4096, &lds[nxt][0][0], w, lane);
            stage_panel(Al + (size_t)(t + 1) * 4096, &lds[nxt][1][0], w, lane);
            stage_panel(BH + (size_t)(t + 1) * 4096, &lds[nxt][2][0], w, lane);
            stage_panel(BL + (size_t)(t + 1) * 4096, &lds[nxt][3][0], w, lane);
        }
        mfma_tile3(&lds[cur][0][0], &lds[cur][1][0], &lds[cur][2][0], &lds[cur][3][0],
                   wm, wn, kq, lm, acc);
    }

    __syncthreads();
    float* eb1 = (float*)&lds[0][0][0];
    float* eb2 = eb1 + 256;
    int*   eix = (int*)(eb2 + 256);

    #pragma unroll
    for (int fm = 0; fm < 4; ++fm) {
        #pragma unroll
        for (int r = 0; r < 4; ++r) {
            float b1v = 3.4e38f, b2v = 3.4e38f; int bi = 0;
            #pragma unroll
            for (int fn = 0; fn < 4; ++fn) {
                const float v = fmaf(-2.0f, acc[fm][fn][r], cbn_l[fn]);
                if (v < b1v) { b2v = b1v; b1v = v; bi = wn * 64 + fn * 16 + lm; }
                else if (v < b2v) b2v = v;
            }
            #pragma unroll
            for (int mk = 1; mk <= 8; mk <<= 1) {
                const float o1 = __shfl_xor(b1v, mk);
                const float o2 = __shfl_xor(b2v, mk);
                const int   oi = __shfl_xor(bi,  mk);
                if (o1 < b1v || (o1 == b1v && oi < bi)) { b2v = fminf(b1v, o2); b1v = o1; bi = oi; }
                else b2v = fminf(b2v, o1);
            }
            const int rl = wm * 64 + fm * 16 + kq * 4 + r;
            if (lm == 0) { eb1[wn * 128 + rl] = b1v; eb2[wn * 128 + rl] = b2v; eix[wn * 128 + rl] = bi; }
        }
    }
    __syncthreads();

    if (tid < 128) {
        const int slot = m0 + tid;
        if (slot < n) {
            const int rl = tid;
            const float a1 = eb1[rl], a2 = eb2[rl]; const int ai = eix[rl];
            const float o1 = eb1[128 + rl], o2 = eb2[128 + rl]; const int oi = eix[128 + rl];
            float B1, B2; int BI;
            if (o1 < a1 || (o1 == a1 && oi < ai)) { B1 = o1; BI = oi; B2 = fminf(a1, o2); }
            else                                  { B1 = a1; BI = ai; B2 = fminf(a2, o1); }
            const int row = list[slot];
            outIdx[row] = (float)BI;
            if (B2 - B1 < TAU2_GAP) {
                const int p = atomicAdd(cnt2, 1);
                if (p < 8192) list2[p] = row;
            }
        }
    }
}

// ---------------------------------------------------------------------------
// fixup2 v2 (tier-2): exact fp32, ONE ROW PER BLOCK (few rows; all blocks
// stream the same W1/W2 concurrently -> L2/L3 broadcast).  Per-kk chain is
// 1 rdlane + 1 pk_fma (8x shorter than the R=8 engine).  8-deep load rings.
// ---------------------------------------------------------------------------
__global__ __launch_bounds__(256)
void fixup2_kernel(const float* __restrict__ x, const float* __restrict__ W1,
                   const float* __restrict__ b1, const float* __restrict__ W2,
                   const float* __restrict__ b2, const float* __restrict__ cbT,
                   const float* __restrict__ cbnorm,
                   const int* __restrict__ cnt2, const int* __restrict__ list2,
                   float* __restrict__ outIdx)
{
    __shared__ float xr[1024];      // 4 KB
    __shared__ float hr[512];       // 2 KB
    __shared__ float er[256];       // 1 KB
    __shared__ float dv[128];
    __shared__ int   di[128];

    const int tid  = threadIdx.x;
    const int lane = tid & 63;
    const int n = *cnt2;

    for (int ri = blockIdx.x; ri < n; ri += gridDim.x) {
        const int row = list2[ri];
        __syncthreads();   // LDS reuse guard across row iterations
        *(float4*)&xr[tid * 4] = *(const float4*)(x + (size_t)row * D_INK + tid * 4);
        __syncthreads();

        // ---- W1: thread owns cols (2t, 2t+1) ----
        {
            const int c2 = tid * 2;
            f32x2 a01 = {0.f, 0.f};
            for (int k0 = 0; k0 < D_INK; k0 += 64) {
                const float xreg = xr[k0 + lane];
                #pragma unroll
                for (int kb = 0; kb < 64; kb += 8) {
                    f32x2 wv[8];
                    #pragma unroll
                    for (int p = 0; p < 8; ++p)
                        wv[p] = *(const f32x2*)&W1[(size_t)(k0 + kb + p) * D_HID + c2];
                    #pragma unroll
                    for (int p = 0; p < 8; ++p) {
                        const float xb = rdlane(xreg, kb + p);
                        a01 = __builtin_elementwise_fma((f32x2){xb, xb}, wv[p], a01);
                    }
                }
            }
            hr[c2]     = fmaxf(a01.x + b1[c2], 0.0f);
            hr[c2 + 1] = fmaxf(a01.y + b1[c2 + 1], 0.0f);
        }
        __syncthreads();

        // ---- W2: thread owns col tid (256 cols) ----
        {
            const int c = tid;
            float a = 0.0f;
            for (int k0 = 0; k0 < D_HID; k0 += 64) {
                const float hreg = hr[k0 + lane];
                #pragma unroll
                for (int kb = 0; kb < 64; kb += 8) {
                    float wv[8];
                    #pragma unroll
                    for (int p = 0; p < 8; ++p)
                        wv[p] = W2[(size_t)(k0 + kb + p) * D_CODE_ + c];
                    #pragma unroll
                    for (int p = 0; p < 8; ++p)
                        a = fmaf(rdlane(hreg, kb + p), wv[p], a);
                }
            }
            er[c] = a + b2[c];
        }
        __syncthreads();

        // ---- distances: threads 0..127, code j = tid ----
        if (tid < 128) {
            const int j = tid;
            float e2 = 0.0f, dt = 0.0f;
            for (int k0 = 0; k0 < D_CODE_; k0 += 64) {
                const float ereg = er[k0 + lane];
                #pragma unroll
                for (int kb = 0; kb < 64; kb += 8) {
                    float cv[8];
                    #pragma unroll
                    for (int p = 0; p < 8; ++p)
                        cv[p] = cbT[(size_t)(k0 + kb + p) * N_CODES_ + j];
                    #pragma unroll
                    for (int p = 0; p < 8; ++p) {
                        const float ev = rdlane(ereg, kb + p);
                        e2 = fmaf(ev, ev, e2);
                        dt = fmaf(ev, cv[p], dt);
                    }
                }
            }
            dv[j] = (e2 - 2.0f * dt) + cbnorm[j];
            di[j] = j;
        }
        __syncthreads();

        // ---- argmin over 128 codes ----
        for (int st = 64; st >= 1; st >>= 1) {
            if (tid < st) {
                const float a = dv[tid], b = dv[tid + st];
                const int  ib = di[tid + st];
                if (b < a || (b == a && ib < di[tid])) { dv[tid] = b; di[tid] = ib; }
            }
            __syncthreads();
        }
        if (tid == 0) outIdx[row] = (float)di[0];
    }
}

// ---------------------------------------------------------------------------
__global__ void finalize_kernel(const float* __restrict__ accum, float* __restrict__ out)
{
    const float inv = 1.0f / (32768.0f * 256.0f);
    const float loss = (accum[0] + accum[1]) * inv;   // commitment == codebook
    out[32768] = loss;
    out[32769] = loss;
    out[32770] = 1.25f * loss;
}

// ---------------------------------------------------------------------------
extern "C" void kernel_launch(void* const* d_in, const int* in_sizes, int n_in,
                              void* d_out, int out_size, void* d_ws, size_t ws_size,
                              hipStream_t stream)
{
    (void)in_sizes; (void)n_in; (void)out_size; (void)ws_size;

    const float* x  = (const float*)d_in[0];  // [32768,1024]
    const float* W1 = (const float*)d_in[1];  // [1024,512]
    const float* b1 = (const float*)d_in[2];  // [512]
    const float* W2 = (const float*)d_in[3];  // [512,256]
    const float* b2 = (const float*)d_in[4];  // [256]
    const float* cb = (const float*)d_in[5];  // [128,256]
    float* out = (float*)d_out;

    char* ws = (char*)d_ws;
    _Float16* W1P   = (_Float16*)(ws + 0);                       // 1 MB
    _Float16* W1Pl  = (_Float16*)(ws + (1u<<20));                // 1 MB
    _Float16* W2P   = (_Float16*)(ws + (2u<<20));                // 256 KB
    _Float16* W2Pl  = (_Float16*)(ws + (2u<<20) + 262144);       // 256 KB
    _Float16* cbP   = (_Float16*)(ws + (2u<<20) + 524288);       // 64 KB
    _Float16* cbPl  = (_Float16*)(ws + (2u<<20) + 589824);       // 64 KB
    float*    cbT   = (float*   )(ws + (2u<<20) + 655360);       // 128 KB
    float*    cbn   = (float*   )(ws + (2u<<20) + 786432);       // 512 B
    float*    accum = (float*   )(ws + (2u<<20) + 786944);       // 64 B
    int*      cnt   = (int*     )(ws + (2u<<20) + 787008);       // 64 B
    int*      cnt2  = (int*     )(ws + (2u<<20) + 787072);       // 64 B
    int*      list  = (int*     )(ws + (2u<<20) + 787136);       // 128 KB
    int*      list2 = (int*     )(ws + (2u<<20) + 918208);       // 32 KB

    _Float16* xP    = (_Float16*)(ws + (size_t)(4u<<20));                    // 64 MB
    _Float16* encP  = (_Float16*)(ws + (size_t)(4u<<20));                    // 16 MB (xP reuse)
    _Float16* xfPh  = (_Float16*)(ws + (size_t)(4u<<20) + 16777216);         // 16 MB (xP reuse)
    _Float16* xfPl  = (_Float16*)(ws + (size_t)(4u<<20) + 33554432);         // 16 MB (xP reuse)
    _Float16* hP    = (_Float16*)(ws + (size_t)(68u<<20));                   // 32 MB
    _Float16* hfPh  = (_Float16*)(ws + (size_t)(68u<<20));                   //  8 MB (hP reuse)
    _Float16* hfPl  = (_Float16*)(ws + (size_t)(68u<<20) + 8388608);         //  8 MB
    _Float16* encfPh= (_Float16*)(ws + (size_t)(68u<<20) + 16777216);        //  4 MB
    _Float16* encfPl= (_Float16*)(ws + (size_t)(68u<<20) + 20971520);        //  4 MB

    prep_cb_kernel<<<N_CODES_, 256, 0, stream>>>(cb, cbP, cbPl, cbT, cbn, accum, cnt, cnt2);
    pack_w_kernel<<<dim3(D_INK / 32, D_HID / 128), 256, 0, stream>>>(W1, W1P, W1Pl, D_INK, D_HID);
    pack_w_kernel<<<dim3(D_HID / 32, D_CODE_ / 128), 256, 0, stream>>>(W2, W2P, W2Pl, D_HID, D_CODE_);
    pack_x_kernel<<<dim3(M_ROWS / 128, D_INK / 128), 256, 0, stream>>>(x, xP);

    gemm1_kernel<<<(M_ROWS / 128) * (D_HID / 128), 256, 0, stream>>>(xP, W1P, b1, hP);
    gemm2_kernel<<<(M_ROWS / 128) * (D_CODE_ / 128), 256, 0, stream>>>(hP, W2P, b2, encP, accum);
    dist_kernel<<<M_ROWS / 128, 256, 0, stream>>>(encP, cbP, cbn, out, accum, cnt, list);

    // tier-1: accurate fp16x3 recompute of flagged rows (MFMA pipe)
    gather_pack_fix_kernel<<<dim3(128, 8), 256, 0, stream>>>(x, list, cnt, xfPh, xfPl);
    gemm1_fix_kernel<<<dim3(64, 4), 256, 0, stream>>>(xfPh, xfPl, W1P, W1Pl, b1, hfPh, hfPl, cnt);
    gemm2_fix_kernel<<<dim3(64, 2), 256, 0, stream>>>(hfPh, hfPl, W2P, W2Pl, b2, encfPh, encfPl, cnt);
    dist_fix_kernel<<<64, 256, 0, stream>>>(encfPh, encfPl, cbP, cbPl, cbn,
                                            list, cnt, out, cnt2, list2);
    // tier-2: exact fp32, one row per block (few rows)
    fixup2_kernel<<<256, 256, 0, stream>>>(x, W1, b1, W2, b2, cbT, cbn, cnt2, list2, out);
    finalize_kernel<<<1, 1, 0, stream>>>(accum, out);
}

// Round 19
// 239.055 us; speedup vs baseline: 1.2881x; 1.1252x over previous
//
#include <hip/hip_runtime.h>
#include <cstddef>
#include <cstdint>

// Problem constants
static constexpr int M_ROWS  = 32768;   // B*T
static constexpr int D_INK   = 1024;
static constexpr int D_HID   = 512;
static constexpr int D_CODE_ = 256;
static constexpr int N_CODES_= 128;

// fp16 single-product pairwise-d2 gap jitter sigma ~= 0.023 -> TAU = 6.5 sigma
static constexpr float TAU_GAP = 0.15f;

using f16x8 = __attribute__((ext_vector_type(8))) _Float16;
using f32x4 = __attribute__((ext_vector_type(4))) float;
using f32x2 = __attribute__((ext_vector_type(2))) float;

__device__ __forceinline__ float rdlane(float v, int kk) {
    return __uint_as_float(__builtin_amdgcn_readlane(__float_as_uint(v), kk));
}

// ---------------------------------------------------------------------------
// Packed panel format: one panel = one (128-row tile) x (32-k step):
//   panel[(kq*128 + rc)*8 + j] = src[tile*128 + rc][ks*32 + kq*8 + j]
// 4096 x fp16 = 8 KB contiguous; frag-linear == the LDS layout the MFMA
// fragment reads want, so global->LDS DMA is fully coalesced AND linear.
// ---------------------------------------------------------------------------

__device__ __forceinline__ void dma16(const void* g, void* l) {
    __builtin_amdgcn_global_load_lds(
        (const __attribute__((address_space(1))) void*)g,
        (__attribute__((address_space(3))) void*)l, 16, 0, 0);
}

// stage one 8 KB panel into LDS: 8 dma16 instrs, 2 per wave, lane-contiguous
__device__ __forceinline__ void stage_panel(const _Float16* __restrict__ p,
                                            _Float16* dst, int w, int lane)
{
    #pragma unroll
    for (int ii = 0; ii < 2; ++ii) {
        const int I = 2 * w + ii;           // 0..7 (wave-uniform)
        dma16(p + (size_t)I * 512 + lane * 8, dst + (size_t)I * 512);
    }
}

// one BK=32 compute step: 4x4 fragment tile per wave, single fp16 product
__device__ __forceinline__ void mfma_tile(const _Float16* sA, const _Float16* sB,
                                          int wm, int wn, int kq, int lm,
                                          f32x4 (&acc)[4][4])
{
    f16x8 a[4];
    #pragma unroll
    for (int fm = 0; fm < 4; ++fm)
        a[fm] = *(const f16x8*)(sA + (kq * 128 + wm * 64 + fm * 16 + lm) * 8);
    #pragma unroll
    for (int fn = 0; fn < 4; ++fn) {
        const f16x8 b = *(const f16x8*)(sB + (kq * 128 + wn * 64 + fn * 16 + lm) * 8);
        #pragma unroll
        for (int fm = 0; fm < 4; ++fm)
            acc[fm][fn] = __builtin_amdgcn_mfma_f32_16x16x32_f16(a[fm], b, acc[fm][fn], 0, 0, 0);
    }
}

// bijective XCD swizzle (nwg % 8 == 0): consecutive logical ids -> same XCD L2
__device__ __forceinline__ int xcd_swz(int bid, int nwg) {
    const int q = nwg >> 3;
    return (bid & 7) * q + (bid >> 3);
}

// ---------------------------------------------------------------------------
// prep: codebook -> packed fp16 panels (B-side) + fp32 transposed copy
// (for coalesced fixup distance reads), exact per-code norms, zero accums.
// ---------------------------------------------------------------------------
__global__ __launch_bounds__(256)
void prep_cb_kernel(const float* __restrict__ cb, _Float16* __restrict__ cbP,
                    float* __restrict__ cbT,
                    float* __restrict__ cbnorm, float* __restrict__ accum,
                    int* __restrict__ cnt)
{
    const int j = blockIdx.x;      // code 0..127
    const int t = threadIdx.x;     // dim 0..255
    const float v = cb[j * D_CODE_ + t];
    const int ks = t >> 5, kq = (t >> 3) & 3, jj = t & 7;
    cbP[((size_t)ks * 512 + kq * 128 + j) * 8 + jj] = (_Float16)v;
    cbT[(size_t)t * N_CODES_ + j] = v;

    __shared__ float sr[256];
    sr[t] = v * v;
    __syncthreads();
    for (int s = 128; s >= 1; s >>= 1) {
        if (t < s) sr[t] += sr[t + s];
        __syncthreads();
    }
    if (t == 0) cbnorm[j] = sr[0];
    if (j == 0 && t < 2) accum[t] = 0.0f;
    if (j == 0 && t == 2) *cnt = 0;
}

// ---------------------------------------------------------------------------
// pack_w: W [K][N] fp32 -> B-side panels (n-tiles of 128, k-steps of 32).
// ---------------------------------------------------------------------------
__global__ __launch_bounds__(256)
void pack_w_kernel(const float* __restrict__ W, _Float16* __restrict__ WP,
                   int Kd, int Nd)
{
    const int ks = blockIdx.x, nt = blockIdx.y;
    const int t = threadIdx.x;
    _Float16* dst = WP + ((size_t)nt * (Kd >> 5) + ks) * 4096;
    #pragma unroll
    for (int half = 0; half < 2; ++half) {
        const int f = half * 256 + t;
        const int nc = f & 127, kq = f >> 7;
        f16x8 v;
        #pragma unroll
        for (int j = 0; j < 8; ++j)
            v[j] = (_Float16)W[(size_t)(ks * 32 + kq * 8 + j) * Nd + nt * 128 + nc];
        *(f16x8*)(dst + (size_t)f * 8) = v;
    }
}

// ---------------------------------------------------------------------------
// pack_x: x fp32 [M][1024] -> A-side fp16 panels.  Coalesced reads,
// LDS-tiled, contiguous panel writes.  grid = (M/128, 8).
// ---------------------------------------------------------------------------
__global__ __launch_bounds__(256)
void pack_x_kernel(const float* __restrict__ X, _Float16* __restrict__ XP)
{
    __shared__ _Float16 sh[128][136];   // 272 B rows: 16B-aligned frag reads
    const int t  = threadIdx.x;
    const int mt = blockIdx.x;          // m-tile
    const int kc = blockIdx.y;          // 128-wide k chunk (4 k-steps)

    const float* src = X + (size_t)mt * 128 * D_INK + kc * 128;
    #pragma unroll
    for (int i = 0; i < 16; ++i) {
        const int idx = i * 256 + t;           // 0..4095
        const int row = idx >> 5, c4 = idx & 31;
        const float4 v = *(const float4*)(src + (size_t)row * D_INK + c4 * 4);
        _Float16* d = &sh[row][c4 * 4];
        d[0] = (_Float16)v.x; d[1] = (_Float16)v.y;
        d[2] = (_Float16)v.z; d[3] = (_Float16)v.w;
    }
    __syncthreads();

    _Float16* dst = XP + ((size_t)mt * 32 + kc * 4) * 4096;
    #pragma unroll
    for (int s = 0; s < 4; ++s) {
        #pragma unroll
        for (int half = 0; half < 2; ++half) {
            const int f = half * 256 + t;
            const int rc = f & 127, kq = f >> 7;
            const f16x8 v = *(const f16x8*)(&sh[rc][s * 32 + kq * 8]);
            *(f16x8*)(dst + (size_t)s * 4096 + (size_t)f * 8) = v;
        }
    }
}

// ---------------------------------------------------------------------------
// GEMM1: h = relu(x @ W1 + b1).  All-packed-DMA staging, dbuf LDS (32 KB),
// one __syncthreads per K-step, 4 blocks/CU, XCD-swizzled n-fast grid.
// Output written directly in gemm2's packed-A layout.
// ---------------------------------------------------------------------------
__global__ __launch_bounds__(256, 4)
void gemm1_kernel(const _Float16* __restrict__ AP, const _Float16* __restrict__ BP,
                  const float* __restrict__ bias, _Float16* __restrict__ CP)
{
    __shared__ _Float16 lds[2][2][4096];   // [buf][A,B]  32 KB

    const int tid  = threadIdx.x;
    const int lane = tid & 63;
    const int w    = tid >> 6;
    const int wm = w >> 1, wn = w & 1;
    const int kq = lane >> 4, lm = lane & 15;

    const int swz = xcd_swz(blockIdx.x, (M_ROWS / 128) * (D_HID / 128));
    const int n0 = (swz & 3) * 128;
    const int m0 = (swz >> 2) * 128;

    const _Float16* Apan = AP + ((size_t)(m0 >> 7) * 32) * 4096;
    const _Float16* Bpan = BP + ((size_t)(n0 >> 7) * 32) * 4096;

    f32x4 acc[4][4] = {};

    stage_panel(Apan, &lds[0][0][0], w, lane);
    stage_panel(Bpan, &lds[0][1][0], w, lane);

    constexpr int NSTEP = D_INK / 32;
    for (int t = 0; t < NSTEP; ++t) {
        const int cur = t & 1, nxt = cur ^ 1;
        __syncthreads();               // buf[cur] staged & visible, buf[nxt] free
        if (t + 1 < NSTEP) {
            stage_panel(Apan + (size_t)(t + 1) * 4096, &lds[nxt][0][0], w, lane);
            stage_panel(Bpan + (size_t)(t + 1) * 4096, &lds[nxt][1][0], w, lane);
        }
        mfma_tile(&lds[cur][0][0], &lds[cur][1][0], wm, wn, kq, lm, acc);
    }

    // epilogue: relu; write in gemm2-packed-A layout (NT=16 over D_HID)
    #pragma unroll
    for (int fn = 0; fn < 4; ++fn) {
        const int col = n0 + wn * 64 + fn * 16 + lm;
        const float bv = bias[col];
        #pragma unroll
        for (int fm = 0; fm < 4; ++fm) {
            #pragma unroll
            for (int r = 0; r < 4; ++r) {
                const int row = m0 + wm * 64 + fm * 16 + kq * 4 + r;
                const float v = fmaxf(acc[fm][fn][r] + bv, 0.0f);
                CP[(((size_t)(row >> 7) * 16 + (col >> 5)) * 512
                    + (size_t)((col >> 3) & 3) * 128 + (row & 127)) * 8 + (col & 7)]
                    = (_Float16)v;
            }
        }
    }
}

// ---------------------------------------------------------------------------
// GEMM2: enc = h @ W2 + b2 (+ sum(enc^2) atomic).  Packed in, packed out.
// ---------------------------------------------------------------------------
__global__ __launch_bounds__(256, 4)
void gemm2_kernel(const _Float16* __restrict__ AP, const _Float16* __restrict__ BP,
                  const float* __restrict__ bias, _Float16* __restrict__ CP,
                  float* __restrict__ accum)
{
    __shared__ _Float16 lds[2][2][4096];

    const int tid  = threadIdx.x;
    const int lane = tid & 63;
    const int w    = tid >> 6;
    const int wm = w >> 1, wn = w & 1;
    const int kq = lane >> 4, lm = lane & 15;

    const int swz = xcd_swz(blockIdx.x, (M_ROWS / 128) * (D_CODE_ / 128));
    const int n0 = (swz & 1) * 128;
    const int m0 = (swz >> 1) * 128;

    const _Float16* Apan = AP + ((size_t)(m0 >> 7) * 16) * 4096;
    const _Float16* Bpan = BP + ((size_t)(n0 >> 7) * 16) * 4096;

    f32x4 acc[4][4] = {};

    stage_panel(Apan, &lds[0][0][0], w, lane);
    stage_panel(Bpan, &lds[0][1][0], w, lane);

    constexpr int NSTEP = D_HID / 32;
    for (int t = 0; t < NSTEP; ++t) {
        const int cur = t & 1, nxt = cur ^ 1;
        __syncthreads();
        if (t + 1 < NSTEP) {
            stage_panel(Apan + (size_t)(t + 1) * 4096, &lds[nxt][0][0], w, lane);
            stage_panel(Bpan + (size_t)(t + 1) * 4096, &lds[nxt][1][0], w, lane);
        }
        mfma_tile(&lds[cur][0][0], &lds[cur][1][0], wm, wn, kq, lm, acc);
    }

    float sumsq = 0.0f;
    #pragma unroll
    for (int fn = 0; fn < 4; ++fn) {
        const int col = n0 + wn * 64 + fn * 16 + lm;
        const float bv = bias[col];
        #pragma unroll
        for (int fm = 0; fm < 4; ++fm) {
            #pragma unroll
            for (int r = 0; r < 4; ++r) {
                const int row = m0 + wm * 64 + fm * 16 + kq * 4 + r;
                const float v = acc[fm][fn][r] + bv;
                sumsq = fmaf(v, v, sumsq);
                CP[(((size_t)(row >> 7) * 8 + (col >> 5)) * 512
                    + (size_t)((col >> 3) & 3) * 128 + (row & 127)) * 8 + (col & 7)]
                    = (_Float16)v;
            }
        }
    }
    #pragma unroll
    for (int mk = 1; mk <= 32; mk <<= 1) sumsq += __shfl_xor(sumsq, mk);
    if (lane == 0) atomicAdd(&accum[1], sumsq);
}

// ---------------------------------------------------------------------------
// dist: dots = enc @ cb^T (one n-block = all 128 codes); argmin epilogue
// with second-best gap flagging + min-term loss sum.
// ---------------------------------------------------------------------------
__global__ __launch_bounds__(256, 4)
void dist_kernel(const _Float16* __restrict__ AP, const _Float16* __restrict__ BP,
                 const float* __restrict__ cbn,
                 float* __restrict__ outIdx, float* __restrict__ accum,
                 int* __restrict__ cnt, int* __restrict__ list)
{
    __shared__ _Float16 lds[2][2][4096];

    const int tid  = threadIdx.x;
    const int lane = tid & 63;
    const int w    = tid >> 6;
    const int wm = w >> 1, wn = w & 1;
    const int kq = lane >> 4, lm = lane & 15;
    const int m0 = blockIdx.x * 128;

    float cbn_l[4];
    #pragma unroll
    for (int fn = 0; fn < 4; ++fn) cbn_l[fn] = cbn[wn * 64 + fn * 16 + lm];

    const _Float16* Apan = AP + ((size_t)(m0 >> 7) * 8) * 4096;

    f32x4 acc[4][4] = {};

    stage_panel(Apan, &lds[0][0][0], w, lane);
    stage_panel(BP,   &lds[0][1][0], w, lane);

    constexpr int NSTEP = D_CODE_ / 32;
    for (int t = 0; t < NSTEP; ++t) {
        const int cur = t & 1, nxt = cur ^ 1;
        __syncthreads();
        if (t + 1 < NSTEP) {
            stage_panel(Apan + (size_t)(t + 1) * 4096, &lds[nxt][0][0], w, lane);
            stage_panel(BP   + (size_t)(t + 1) * 4096, &lds[nxt][1][0], w, lane);
        }
        mfma_tile(&lds[cur][0][0], &lds[cur][1][0], wm, wn, kq, lm, acc);
    }

    __syncthreads();   // all LDS reads done before reuse as epilogue scratch
    float* eb1 = (float*)&lds[0][0][0];        // [2][128]
    float* eb2 = eb1 + 256;
    int*   eix = (int*)(eb2 + 256);

    #pragma unroll
    for (int fm = 0; fm < 4; ++fm) {
        #pragma unroll
        for (int r = 0; r < 4; ++r) {
            float b1v = 3.4e38f, b2v = 3.4e38f; int bi = 0;
            #pragma unroll
            for (int fn = 0; fn < 4; ++fn) {
                const float v = fmaf(-2.0f, acc[fm][fn][r], cbn_l[fn]);
                if (v < b1v) { b2v = b1v; b1v = v; bi = wn * 64 + fn * 16 + lm; }
                else if (v < b2v) b2v = v;
            }
            #pragma unroll
            for (int mk = 1; mk <= 8; mk <<= 1) {
                const float o1 = __shfl_xor(b1v, mk);
                const float o2 = __shfl_xor(b2v, mk);
                const int   oi = __shfl_xor(bi,  mk);
                if (o1 < b1v || (o1 == b1v && oi < bi)) { b2v = fminf(b1v, o2); b1v = o1; bi = oi; }
                else b2v = fminf(b2v, o1);
            }
            const int rl = wm * 64 + fm * 16 + kq * 4 + r;
            if (lm == 0) { eb1[wn * 128 + rl] = b1v; eb2[wn * 128 + rl] = b2v; eix[wn * 128 + rl] = bi; }
        }
    }
    __syncthreads();

    if (tid < 128) {
        const int rl = tid;
        const float a1 = eb1[rl], a2 = eb2[rl]; const int ai = eix[rl];
        const float o1 = eb1[128 + rl], o2 = eb2[128 + rl]; const int oi = eix[128 + rl];
        float B1, B2; int BI;
        if (o1 < a1 || (o1 == a1 && oi < ai)) { B1 = o1; BI = oi; B2 = fminf(a1, o2); }
        else                                  { B1 = a1; BI = ai; B2 = fminf(a2, o1); }
        outIdx[m0 + rl] = (float)BI;
        if (B2 - B1 < TAU_GAP) {
            const int p = atomicAdd(cnt, 1);
            if (p < 32768) list[p] = m0 + rl;
        }
        float s = B1;
        #pragma unroll
        for (int mk = 1; mk <= 32; mk <<= 1) s += __shfl_xor(s, mk);
        if (lane == 0) atomicAdd(&accum[0], s);
    }
}

// ---------------------------------------------------------------------------
// fixup v9: exact fp32 recompute of flagged rows, 4 rows/group, 256 threads.
// Same v6 engine (register weight reuse via rdlane, pk_fma, 8-deep load
// rings) but R=4: per-kk serial path halves (1 load + 4 rdlane + 4 pk_fma);
// W1/W2/cbT (2.6 MB) stay L2-resident so the doubled re-read is cheap.
// 32 KB LDS -> 4 blocks/CU -> all ~600 groups co-resident (single round).
// Per-output accumulation order: single k-ascending chain (identical
// numerics to all passing rounds).
// ---------------------------------------------------------------------------
__global__ __launch_bounds__(256, 4)
void fixup_kernel(const float* __restrict__ x, const float* __restrict__ W1,
                  const float* __restrict__ b1, const float* __restrict__ W2,
                  const float* __restrict__ b2, const float* __restrict__ cbT,
                  const float* __restrict__ cbnorm,
                  const int* __restrict__ cnt, const int* __restrict__ list,
                  float* __restrict__ outIdx)
{
    __shared__ float xr[4][1024];   // 16 KB
    __shared__ float hr[4][512];    //  8 KB
    __shared__ float er[4][256];    //  4 KB
    __shared__ float dv[4][128];    //  2 KB
    __shared__ int   di[4][128];    //  2 KB   -> 32 KB total

    const int tid  = threadIdx.x;
    const int lane = tid & 63;
    const int n = *cnt;
    const int ngroups = (n + 3) >> 2;

    for (int g = blockIdx.x; g < ngroups; g += gridDim.x) {
        const int base = g * 4;
        const int nr = (n - base < 4) ? (n - base) : 4;
        __syncthreads();   // LDS reuse guard across group iterations
        #pragma unroll
        for (int r = 0; r < 4; ++r) {
            if (r < nr) {
                const int row = list[base + r];
                *(float4*)&xr[r][tid * 4] =
                    *(const float4*)(x + (size_t)row * D_INK + tid * 4);
            }
        }
        __syncthreads();

        // ---- W1 phase: thread owns cols (2t, 2t+1), all 4 rows ----
        {
            const int c2 = tid * 2;
            f32x2 a01[4] = {};
            for (int k0 = 0; k0 < D_INK; k0 += 64) {
                float xreg[4];
                #pragma unroll
                for (int r = 0; r < 4; ++r) xreg[r] = xr[r][k0 + lane];
                #pragma unroll
                for (int kb = 0; kb < 64; kb += 8) {
                    f32x2 wv[8];
                    #pragma unroll
                    for (int p = 0; p < 8; ++p)
                        wv[p] = *(const f32x2*)&W1[(size_t)(k0 + kb + p) * D_HID + c2];
                    #pragma unroll
                    for (int p = 0; p < 8; ++p) {
                        const int kk = kb + p;
                        #pragma unroll
                        for (int r = 0; r < 4; ++r) {
                            const float xb = rdlane(xreg[r], kk);
                            a01[r] = __builtin_elementwise_fma((f32x2){xb, xb}, wv[p], a01[r]);
                        }
                    }
                }
            }
            #pragma unroll
            for (int r = 0; r < 4; ++r) {
                hr[r][c2]     = fmaxf(a01[r].x + b1[c2], 0.0f);
                hr[r][c2 + 1] = fmaxf(a01[r].y + b1[c2 + 1], 0.0f);
            }
        }
        __syncthreads();

        // ---- W2 phase: thread owns cols (cc, cc+1), rows half*2..+1 ----
        {
            const int cc = (tid & 127) * 2;
            const int half = tid >> 7;
            f32x2 a2[2] = {};
            for (int k0 = 0; k0 < D_HID; k0 += 64) {
                float hreg[2];
                #pragma unroll
                for (int q = 0; q < 2; ++q) hreg[q] = hr[half * 2 + q][k0 + lane];
                #pragma unroll
                for (int kb = 0; kb < 64; kb += 8) {
                    f32x2 wv[8];
                    #pragma unroll
                    for (int p = 0; p < 8; ++p)
                        wv[p] = *(const f32x2*)&W2[(size_t)(k0 + kb + p) * D_CODE_ + cc];
                    #pragma unroll
                    for (int p = 0; p < 8; ++p) {
                        const int kk = kb + p;
                        #pragma unroll
                        for (int q = 0; q < 2; ++q) {
                            const float hb = rdlane(hreg[q], kk);
                            a2[q] = __builtin_elementwise_fma((f32x2){hb, hb}, wv[p], a2[q]);
                        }
                    }
                }
            }
            #pragma unroll
            for (int q = 0; q < 2; ++q) {
                er[half * 2 + q][cc]     = a2[q].x + b2[cc];
                er[half * 2 + q][cc + 1] = a2[q].y + b2[cc + 1];
            }
        }
        __syncthreads();

        // ---- distance phase: thread owns code j, rows half*2..+1 ----
        {
            const int j = tid & 127;
            const int half = tid >> 7;
            float e2[2] = {0.0f, 0.0f}, dt[2] = {0.0f, 0.0f};
            for (int k0 = 0; k0 < D_CODE_; k0 += 64) {
                float ereg[2];
                #pragma unroll
                for (int q = 0; q < 2; ++q) ereg[q] = er[half * 2 + q][k0 + lane];
                #pragma unroll
                for (int kb = 0; kb < 64; kb += 8) {
                    float cv[8];
                    #pragma unroll
                    for (int p = 0; p < 8; ++p)
                        cv[p] = cbT[(size_t)(k0 + kb + p) * N_CODES_ + j];
                    #pragma unroll
                    for (int p = 0; p < 8; ++p) {
                        const int kk = kb + p;
                        #pragma unroll
                        for (int q = 0; q < 2; ++q) {
                            const float ev = rdlane(ereg[q], kk);
                            e2[q] = fmaf(ev, ev, e2[q]);
                            dt[q] = fmaf(ev, cv[p], dt[q]);
                        }
                    }
                }
            }
            #pragma unroll
            for (int q = 0; q < 2; ++q) {
                dv[half * 2 + q][j] = (e2[q] - 2.0f * dt[q]) + cbnorm[j];
                di[half * 2 + q][j] = j;
            }
        }
        __syncthreads();

        // ---- argmin reduce: 2 rows per pass (256 = 2 x 128), 2 passes ----
        #pragma unroll
        for (int pass = 0; pass < 2; ++pass) {
            const int r = pass * 2 + (tid >> 7);
            const int i = tid & 127;
            for (int st = 64; st >= 1; st >>= 1) {
                if (i < st) {
                    const float a = dv[r][i], b = dv[r][i + st];
                    const int  ib = di[r][i + st];
                    if (b < a || (b == a && ib < di[r][i])) { dv[r][i] = b; di[r][i] = ib; }
                }
                __syncthreads();
            }
        }
        if (tid < nr) outIdx[list[base + tid]] = (float)di[tid][0];
    }
}

// ---------------------------------------------------------------------------
__global__ void finalize_kernel(const float* __restrict__ accum, float* __restrict__ out)
{
    const float inv = 1.0f / (32768.0f * 256.0f);
    const float loss = (accum[0] + accum[1]) * inv;   // commitment == codebook
    out[32768] = loss;
    out[32769] = loss;
    out[32770] = 1.25f * loss;
}

// ---------------------------------------------------------------------------
extern "C" void kernel_launch(void* const* d_in, const int* in_sizes, int n_in,
                              void* d_out, int out_size, void* d_ws, size_t ws_size,
                              hipStream_t stream)
{
    (void)in_sizes; (void)n_in; (void)out_size; (void)ws_size;

    const float* x  = (const float*)d_in[0];  // [32768,1024]
    const float* W1 = (const float*)d_in[1];  // [1024,512]
    const float* b1 = (const float*)d_in[2];  // [512]
    const float* W2 = (const float*)d_in[3];  // [512,256]
    const float* b2 = (const float*)d_in[4];  // [256]
    const float* cb = (const float*)d_in[5];  // [128,256]
    float* out = (float*)d_out;

    // workspace layout (bytes); encP overlaps xP (xP dead after gemm1)
    char* ws = (char*)d_ws;
    _Float16* W1P  = (_Float16*)(ws + 0);                 // 1 MB   (4 nt x 32 ks)
    _Float16* W2P  = (_Float16*)(ws + 1048576);           // 256 KB (2 nt x 16 ks)
    _Float16* cbP  = (_Float16*)(ws + 1310720);           // 64 KB  (1 nt x 8 ks)
    float*    cbn  = (float*   )(ws + 1376256);           // 512 B
    float*    accum= (float*   )(ws + 1376768);           // 64 B
    int*      cnt  = (int*     )(ws + 1376832);           // 64 B
    int*      list = (int*     )(ws + 1376896);           // 128 KB
    float*    cbT  = (float*   )(ws + 1507968);           // 128 KB fp32 [256][128]
    _Float16* xP   = (_Float16*)(ws + (size_t)(2u<<20));              // 64 MB
    _Float16* encP = (_Float16*)(ws + (size_t)(2u<<20));              // 16 MB (reuse)
    _Float16* hP   = (_Float16*)(ws + (size_t)(2u<<20) + 67108864);   // 32 MB

    prep_cb_kernel<<<N_CODES_, 256, 0, stream>>>(cb, cbP, cbT, cbn, accum, cnt);
    pack_w_kernel<<<dim3(D_INK / 32, D_HID / 128), 256, 0, stream>>>(W1, W1P, D_INK, D_HID);
    pack_w_kernel<<<dim3(D_HID / 32, D_CODE_ / 128), 256, 0, stream>>>(W2, W2P, D_HID, D_CODE_);
    pack_x_kernel<<<dim3(M_ROWS / 128, D_INK / 128), 256, 0, stream>>>(x, xP);

    gemm1_kernel<<<(M_ROWS / 128) * (D_HID / 128), 256, 0, stream>>>(xP, W1P, b1, hP);
    gemm2_kernel<<<(M_ROWS / 128) * (D_CODE_ / 128), 256, 0, stream>>>(hP, W2P, b2, encP, accum);
    dist_kernel<<<M_ROWS / 128, 256, 0, stream>>>(encP, cbP, cbn, out, accum, cnt, list);
    fixup_kernel<<<1024, 256, 0, stream>>>(x, W1, b1, W2, b2, cbT, cbn, cnt, list, out);
    finalize_kernel<<<1, 1, 0, stream>>>(accum, out);
}